// Round 10
// baseline (1117.415 us; speedup 1.0000x reference)
//
#include <hip/hip_runtime.h>

#define NPTS 100000
#define CC   64
#define KK   27
#define TOT  (KK * NPTS)        // 2,700,000 edges
#define EPSBN 1e-5f
#define MT   128                // dst rows per conv block
#define NB   ((NPTS + MT - 1) / MT)   // 782 dst-blocks (= buckets per k)
#define CAP  200                // bucket capacity: Poisson(128) + 6.4 sigma

#define CHUNK  12500            // edges per partition block (divides NPTS)
#define NCH    (TOT / CHUNK)    // 216 chunks total

#define XBLK   (NPTS * CC / 1024)       // 6250 blocks for x conversion
#define WBLK   (2 * KK * CC * CC / 256) // 864 blocks for W prep

// fixed-point scale for the LDS integer accumulator (ds_add_u32 is native;
// fp32 LDS atomicAdd compiles to a CAS retry loop -> 7x slowdown, round 1)
#define FPSCALE 262144.0f               // 2^18
#define FPINV   3.814697265625e-06f     // 2^-18
#define FPMAGIC 12582912.0f             // 1.5 * 2^23
#define FPBITS  0x4B400000

typedef float          f32x4  __attribute__((ext_vector_type(4)));
typedef short          bf16x8 __attribute__((ext_vector_type(8)));
typedef unsigned int   u32x4  __attribute__((ext_vector_type(4)));
typedef unsigned short u16x4  __attribute__((ext_vector_type(4)));
typedef int            i32x4  __attribute__((ext_vector_type(4)));

__device__ __forceinline__ unsigned short f2bf(float f) {
    unsigned int u = __float_as_uint(f);
    u = (u + 0x7fffu + ((u >> 16) & 1u)) >> 16;
    return (unsigned short)u;
}

__device__ __forceinline__ int f2fix(float v) {
    return __float_as_int(fmaf(v, FPSCALE, FPMAGIC)) - FPBITS;
}

// ------------- fused prep (x->bf16, W->Wt) + single-pass CSR partition ------------
__global__ __launch_bounds__(256) void k_prep_part(
    const float* __restrict__ x,
    const float* __restrict__ W1, const float* __restrict__ W2,
    const int* __restrict__ out_idx, const int* __restrict__ in_idx,
    unsigned short* __restrict__ xb,
    unsigned short* __restrict__ Wt1, unsigned short* __restrict__ Wt2,
    int* __restrict__ cnt, unsigned* __restrict__ entries) {
    __shared__ int lc[NB];
    const int t = threadIdx.x;
    int b = blockIdx.x;
    if (b < XBLK) {
        int id = b * 256 + t;
        f32x4 v = ((const f32x4*)x)[id];
        u16x4 o;
#pragma unroll
        for (int j = 0; j < 4; ++j) o[j] = f2bf(v[j]);
        ((u16x4*)xb)[id] = o;
        return;
    }
    if (b < XBLK + WBLK) {
        int id = (b - XBLK) * 256 + t;
        int which = id / (KK * CC * CC);
        int r = id % (KK * CC * CC);
        int k = r / (CC * CC);
        int rem = r % (CC * CC);
        int cin = rem / CC, cout = rem % CC;
        const float* W = which ? W2 : W1;
        unsigned short* Wt = which ? Wt2 : Wt1;
        Wt[k * CC * CC + cout * CC + cin] = f2bf(W[r]);
        return;
    }
    b -= XBLK + WBLK;
    for (int i = t; i < NB; i += 256) lc[i] = 0;
    __syncthreads();
    const int j0 = b * CHUNK;
    const int k  = j0 / NPTS;                  // CHUNK divides NPTS
    const i32x4* dsrc = (const i32x4*)(out_idx + j0);
    const i32x4* ssrc = (const i32x4*)(in_idx + j0);
    for (int ii = t; ii < CHUNK / 4; ii += 256) {
        i32x4 d = dsrc[ii];
#pragma unroll
        for (int q = 0; q < 4; ++q) atomicAdd(&lc[d[q] >> 7], 1);
    }
    __syncthreads();
    for (int i = t; i < NB; i += 256)
        lc[i] = atomicAdd(&cnt[k * NB + i], lc[i]);   // lc[i] := global base
    __syncthreads();
    for (int ii = t; ii < CHUNK / 4; ii += 256) {
        i32x4 d4 = dsrc[ii];
        i32x4 s4 = ssrc[ii];
#pragma unroll
        for (int q = 0; q < 4; ++q) {
            int d = d4[q];
            int bb = d >> 7;
            int pos = atomicAdd(&lc[bb], 1);
            if (pos < CAP)
                entries[(size_t)(k * NB + bb) * CAP + pos] =
                    ((unsigned)(d & 127) << 17) | (unsigned)s4[q];
        }
    }
}

// ---------------- r7-proven conv accumulate body (3-stage gather pipeline) ---------
__device__ __forceinline__ void conv_accum(
    const unsigned short* __restrict__ xsrc,   // [N][64] bf16 (xbf or a1)
    const unsigned short* __restrict__ Wt,     // [27][64][64] bf16
    const int* __restrict__ cnt,
    const unsigned* __restrict__ entries,
    int* ylds, const int blk,
    const int wave, const int quad, const int l16)
{
    const unsigned short* xq = xsrc + quad * 8;
    for (int k = wave; k < KK; k += 4) {
        const int bkt = k * NB + blk;
        const size_t start = (size_t)bkt * CAP;
        int E = cnt[bkt];
        E = E > CAP ? CAP : E;
        if (E == 0) continue;
        const int emax = E - 1;

        bf16x8 bfr[4][2];
        const unsigned short* wk = Wt + k * (CC * CC) + l16 * CC + quad * 8;
#pragma unroll
        for (int nt = 0; nt < 4; ++nt) {
            bfr[nt][0] = *(const bf16x8*)(wk + nt * 16 * CC);
            bfr[nt][1] = *(const bf16x8*)(wk + nt * 16 * CC + 32);
        }

        const int ntile = (E + 31) >> 5;

        unsigned eA0 = entries[start + min(l16, emax)];
        unsigned eB0 = entries[start + min(16 + l16, emax)];
        bf16x8 fc[2][2], fn[2][2];
        {
            const unsigned short* p0 = xq + (eA0 & 0x1FFFFu) * CC;
            const unsigned short* p1 = xq + (eB0 & 0x1FFFFu) * CC;
            fc[0][0] = *(const bf16x8*)p0;
            fc[0][1] = *(const bf16x8*)(p0 + 32);
            fc[1][0] = *(const bf16x8*)p1;
            fc[1][1] = *(const bf16x8*)(p1 + 32);
        }
        unsigned eA1 = entries[start + min(32 + l16, emax)];
        unsigned eB1 = entries[start + min(48 + l16, emax)];
        {
            const unsigned short* p0 = xq + (eA1 & 0x1FFFFu) * CC;
            const unsigned short* p1 = xq + (eB1 & 0x1FFFFu) * CC;
            fn[0][0] = *(const bf16x8*)p0;
            fn[0][1] = *(const bf16x8*)(p0 + 32);
            fn[1][0] = *(const bf16x8*)p1;
            fn[1][1] = *(const bf16x8*)(p1 + 32);
        }
        unsigned eA2 = entries[start + min(64 + l16, emax)];
        unsigned eB2 = entries[start + min(80 + l16, emax)];

        for (int t = 0; t < ntile; ++t) {
            const int tb = t * 32;
            unsigned dp[2][4];
#pragma unroll
            for (int rr = 0; rr < 4; ++rr) {
                dp[0][rr] = (unsigned)__shfl((int)eA0, quad * 4 + rr, 16);
                dp[1][rr] = (unsigned)__shfl((int)eB0, quad * 4 + rr, 16);
            }
            bf16x8 fp[2][2];
            {
                const unsigned short* p0 = xq + (eA2 & 0x1FFFFu) * CC;
                const unsigned short* p1 = xq + (eB2 & 0x1FFFFu) * CC;
                fp[0][0] = *(const bf16x8*)p0;
                fp[0][1] = *(const bf16x8*)(p0 + 32);
                fp[1][0] = *(const bf16x8*)p1;
                fp[1][1] = *(const bf16x8*)(p1 + 32);
            }
            unsigned eA3 = entries[start + min(tb + 96 + l16, emax)];
            unsigned eB3 = entries[start + min(tb + 112 + l16, emax)];

            f32x4 acc[2][4];
#pragma unroll
            for (int mt = 0; mt < 2; ++mt)
#pragma unroll
                for (int nt = 0; nt < 4; ++nt) acc[mt][nt] = (f32x4){0.f, 0.f, 0.f, 0.f};
            __builtin_amdgcn_s_setprio(1);
#pragma unroll
            for (int mt = 0; mt < 2; ++mt)
#pragma unroll
                for (int nt = 0; nt < 4; ++nt) {
                    acc[mt][nt] = __builtin_amdgcn_mfma_f32_16x16x32_bf16(
                        fc[mt][0], bfr[nt][0], acc[mt][nt], 0, 0, 0);
                    acc[mt][nt] = __builtin_amdgcn_mfma_f32_16x16x32_bf16(
                        fc[mt][1], bfr[nt][1], acc[mt][nt], 0, 0, 0);
                }
            __builtin_amdgcn_s_setprio(0);

#pragma unroll
            for (int mt = 0; mt < 2; ++mt)
#pragma unroll
                for (int rr = 0; rr < 4; ++rr) {
                    int slot = tb + mt * 16 + quad * 4 + rr;
                    if (slot < E) {
                        int row = (int)(dp[mt][rr] >> 17);
                        int xv = (row & 1) << 4;
                        unsigned* yp = (unsigned*)&ylds[row * 64 + l16];
                        atomicAdd(yp + (0 ^ xv),  (unsigned)f2fix(acc[mt][0][rr]));
                        atomicAdd(yp + (16 ^ xv), (unsigned)f2fix(acc[mt][1][rr]));
                        atomicAdd(yp + (32 ^ xv), (unsigned)f2fix(acc[mt][2][rr]));
                        atomicAdd(yp + (48 ^ xv), (unsigned)f2fix(acc[mt][3][rr]));
                    }
                }
            fc[0][0] = fn[0][0]; fc[0][1] = fn[0][1];
            fc[1][0] = fn[1][0]; fc[1][1] = fn[1][1];
            fn[0][0] = fp[0][0]; fn[0][1] = fp[0][1];
            fn[1][0] = fp[1][0]; fn[1][1] = fp[1][1];
            eA0 = eA1; eB0 = eB1;
            eA1 = eA2; eB1 = eB2;
            eA2 = eA3; eB2 = eB3;
        }
    }
}

// hand-rolled grid barrier: all NB blocks co-resident BY CONSTRUCTION
// (launch_bounds(256,4): VGPR<=128, LDS 34.8KB -> 4 blocks/CU x 256 CU = 1024 >= 782).
// release threadfence (L2 writeback) before arrive; agent-scope acquire spin.
__device__ __forceinline__ void grid_bar(unsigned* bar, unsigned target) {
    __syncthreads();
    if (threadIdx.x == 0) {
        __threadfence();
        __hip_atomic_fetch_add(bar, 1u, __ATOMIC_RELEASE, __HIP_MEMORY_SCOPE_AGENT);
        while (__hip_atomic_load(bar, __ATOMIC_ACQUIRE, __HIP_MEMORY_SCOPE_AGENT) < target)
            __builtin_amdgcn_s_sleep(8);
    }
    __syncthreads();
}

// ---------------- mega: conv1 -> BN1+ReLU -> conv2 -> BN2 + residual --------------
// y lives entirely in LDS (never hits HBM); a1 goes through a FRESH global buffer
// (no stale clean lines in remote L2s); cross-XCD handoff fenced via grid_bar.
__global__ __launch_bounds__(256, 4) void k_mega(
    const unsigned short* __restrict__ xb,    // [N][64] bf16
    const unsigned short* __restrict__ Wt1,
    const unsigned short* __restrict__ Wt2,
    const int* __restrict__ cnt,
    const unsigned* __restrict__ entries,
    unsigned short* __restrict__ a1,          // [N][64] bf16 (fresh buffer)
    const float* __restrict__ x,
    const float* __restrict__ gamma1, const float* __restrict__ beta1,
    const float* __restrict__ gamma2, const float* __restrict__ beta2,
    float* __restrict__ sums,                 // [256]: L1 sum/sumsq, L2 sum/sumsq
    unsigned* __restrict__ bar,               // [3] barrier counters (zeroed)
    float* __restrict__ out)
{
    __shared__ int   ylds[MT * 64];           // 32768 B
    __shared__ float ssum[2][4][64];          // 2048 B

    const int tid  = threadIdx.x;
    const int lane = tid & 63;
    const int wave = tid >> 6;                // 0..3
    const int quad = lane >> 4;
    const int l16  = lane & 15;
    const int blk  = blockIdx.x;
    const int i0   = blk << 7;
    const int col  = tid & 63;
    const int rg   = tid >> 6;                // 0..3 -> 32 rows each

    for (int i = tid; i < MT * 64; i += 256) ylds[i] = 0;
    __syncthreads();

    // ---- layer 1 conv ----
    conv_accum(xb, Wt1, cnt, entries, ylds, blk, wave, quad, l16);
    __syncthreads();

    // ---- BN1 stats (keep ylds intact) ----
    {
        float s = 0.f, q = 0.f;
#pragma unroll
        for (int i = 0; i < 32; ++i) {
            int row = rg * 32 + i;
            float v = (float)ylds[row * 64 + (col ^ ((row & 1) << 4))] * FPINV;
            s += v; q += v * v;        // rows >= NPTS are zero -> harmless
        }
        ssum[0][rg][col] = s;
        ssum[1][rg][col] = q;
        __syncthreads();
        if (tid < 128) {
            int which = tid >> 6, c = tid & 63;
            float a = ssum[which][0][c] + ssum[which][1][c] +
                      ssum[which][2][c] + ssum[which][3][c];
            atomicAdd(&sums[which * 64 + c], a);
        }
    }
    grid_bar(&bar[0], NB);

    // ---- BN1 finalize + ReLU -> a1 (bf16); zero ylds for conv2 ----
    {
        float su = __hip_atomic_load(&sums[col],      __ATOMIC_RELAXED, __HIP_MEMORY_SCOPE_AGENT);
        float sq = __hip_atomic_load(&sums[64 + col], __ATOMIC_RELAXED, __HIP_MEMORY_SCOPE_AGENT);
        float mu  = su * (1.0f / NPTS);
        float var = sq * (1.0f / NPTS) - mu * mu;
        float sc = gamma1[col] * rsqrtf(var + EPSBN);
        float bi = beta1[col] - mu * sc;
#pragma unroll
        for (int i = 0; i < 32; ++i) {
            int row = rg * 32 + i;
            int idx = row * 64 + (col ^ ((row & 1) << 4));
            float v = (float)ylds[idx] * FPINV;
            float r = fmaxf(fmaf(v, sc, bi), 0.f);
            int gr = i0 + row;
            if (gr < NPTS) a1[(long)gr * CC + col] = f2bf(r);
            ylds[idx] = 0;
        }
    }
    grid_bar(&bar[1], NB);                    // a1 visible device-wide

    // ---- layer 2 conv (gather a1) ----
    conv_accum(a1, Wt2, cnt, entries, ylds, blk, wave, quad, l16);
    __syncthreads();

    // ---- BN2 stats ----
    {
        float s = 0.f, q = 0.f;
#pragma unroll
        for (int i = 0; i < 32; ++i) {
            int row = rg * 32 + i;
            float v = (float)ylds[row * 64 + (col ^ ((row & 1) << 4))] * FPINV;
            s += v; q += v * v;
        }
        ssum[0][rg][col] = s;
        ssum[1][rg][col] = q;
        __syncthreads();
        if (tid < 128) {
            int which = tid >> 6, c = tid & 63;
            float a = ssum[which][0][c] + ssum[which][1][c] +
                      ssum[which][2][c] + ssum[which][3][c];
            atomicAdd(&sums[128 + which * 64 + c], a);
        }
    }
    grid_bar(&bar[2], NB);

    // ---- BN2 finalize + residual + ReLU -> out ----
    {
        float su = __hip_atomic_load(&sums[128 + col], __ATOMIC_RELAXED, __HIP_MEMORY_SCOPE_AGENT);
        float sq = __hip_atomic_load(&sums[192 + col], __ATOMIC_RELAXED, __HIP_MEMORY_SCOPE_AGENT);
        float mu  = su * (1.0f / NPTS);
        float var = sq * (1.0f / NPTS) - mu * mu;
        float sc = gamma2[col] * rsqrtf(var + EPSBN);
        float bi = beta2[col] - mu * sc;
#pragma unroll
        for (int i = 0; i < 32; ++i) {
            int row = rg * 32 + i;
            float v = (float)ylds[row * 64 + (col ^ ((row & 1) << 4))] * FPINV;
            int gr = i0 + row;
            if (gr < NPTS) {
                float xv = x[(long)gr * CC + col];
                out[(long)gr * CC + col] = fmaxf(fmaf(v, sc, bi) + xv, 0.f);
            }
        }
    }
}

extern "C" void kernel_launch(void* const* d_in, const int* in_sizes, int n_in,
                              void* d_out, int out_size, void* d_ws, size_t ws_size,
                              hipStream_t stream) {
    const float* x      = (const float*)d_in[0];
    // d_in[1] = norm_points (unused by the reference math)
    const float* W1     = (const float*)d_in[2];
    const float* gamma1 = (const float*)d_in[3];
    const float* beta1  = (const float*)d_in[4];
    const float* W2     = (const float*)d_in[5];
    const float* gamma2 = (const float*)d_in[6];
    const float* beta2  = (const float*)d_in[7];
    const int* in_idx   = (const int*)d_in[8];
    const int* out_idx  = (const int*)d_in[9];
    float* out = (float*)d_out;

    char* w = (char*)d_ws;
    size_t off = 0;
    auto alloc = [&](size_t bytes) -> char* {
        off = (off + 255) & ~(size_t)255;
        char* p = w + off;
        off += bytes;
        return p;
    };
    int*      cnt  = (int*)     alloc((size_t)KK * NB * 4);
    unsigned* bar  = (unsigned*)alloc(3 * 4);
    float*    sums = (float*)   alloc(256 * 4);   // [0:128) L1, [128:256) L2
    unsigned* entries = (unsigned*)alloc((size_t)KK * NB * CAP * 4);
    unsigned short* xbf = (unsigned short*)alloc((size_t)NPTS * CC * 2);
    unsigned short* a1  = (unsigned short*)alloc((size_t)NPTS * CC * 2);
    unsigned short* Wt1 = (unsigned short*)alloc((size_t)KK * CC * CC * 2);
    unsigned short* Wt2 = (unsigned short*)alloc((size_t)KK * CC * CC * 2);

    // zero cnt + bar + sums in one shot (contiguous incl. alignment gaps)
    size_t zlen = (size_t)((char*)(sums + 256) - (char*)cnt);
    hipMemsetAsync(cnt, 0, zlen, stream);

    k_prep_part<<<XBLK + WBLK + NCH, 256, 0, stream>>>(
        x, W1, W2, out_idx, in_idx, xbf, Wt1, Wt2, cnt, entries);

    k_mega<<<NB, 256, 0, stream>>>(
        xbf, Wt1, Wt2, cnt, entries, a1, x,
        gamma1, beta1, gamma2, beta2, sums, bar, out);
}

// Round 11
// 838.931 us; speedup vs baseline: 1.3320x; 1.3320x over previous
//
#include <hip/hip_runtime.h>

#define NPTS 100000
#define CC   64
#define KK   27
#define TOT  (KK * NPTS)        // 2,700,000 edges
#define EPSBN 1e-5f
#define MT   128                // dst rows per conv block
#define NB   ((NPTS + MT - 1) / MT)   // 782 dst-blocks (= buckets per k)
#define CAP  200                // bucket capacity: Poisson(128) + 6.4 sigma

#define CHUNK  12500            // edges per partition block (divides NPTS)
#define NCH    (TOT / CHUNK)    // 216 chunks total

#define XBLK   (NPTS * CC / 1024)       // 6250 blocks for x conversion
#define WBLK   (2 * KK * CC * CC / 256) // 864 blocks for W prep

// fixed-point scale for the LDS integer accumulator (ds_add_u32 is native;
// fp32 LDS atomicAdd compiles to a CAS retry loop -> 7x slowdown, round 1)
#define FPSCALE 262144.0f               // 2^18
#define FPINV   3.814697265625e-06f     // 2^-18
#define FPMAGIC 12582912.0f             // 1.5 * 2^23
#define FPBITS  0x4B400000

typedef float          f32x4  __attribute__((ext_vector_type(4)));
typedef short          bf16x8 __attribute__((ext_vector_type(8)));
typedef unsigned int   u32x4  __attribute__((ext_vector_type(4)));
typedef unsigned short u16x4  __attribute__((ext_vector_type(4)));
typedef int            i32x4  __attribute__((ext_vector_type(4)));

__device__ __forceinline__ unsigned short f2bf(float f) {
    unsigned int u = __float_as_uint(f);
    u = (u + 0x7fffu + ((u >> 16) & 1u)) >> 16;
    return (unsigned short)u;
}

__device__ __forceinline__ int f2fix(float v) {
    return __float_as_int(fmaf(v, FPSCALE, FPMAGIC)) - FPBITS;
}

// ------------- fused prep (x->bf16, W->Wt) + single-pass CSR partition ------------
__global__ __launch_bounds__(256) void k_prep_part(
    const float* __restrict__ x,
    const float* __restrict__ W1, const float* __restrict__ W2,
    const int* __restrict__ out_idx, const int* __restrict__ in_idx,
    unsigned short* __restrict__ xb,
    unsigned short* __restrict__ Wt1, unsigned short* __restrict__ Wt2,
    int* __restrict__ cnt, unsigned* __restrict__ entries) {
    __shared__ int lc[NB];
    const int t = threadIdx.x;
    int b = blockIdx.x;
    if (b < XBLK) {
        int id = b * 256 + t;
        f32x4 v = ((const f32x4*)x)[id];
        u16x4 o;
#pragma unroll
        for (int j = 0; j < 4; ++j) o[j] = f2bf(v[j]);
        ((u16x4*)xb)[id] = o;
        return;
    }
    if (b < XBLK + WBLK) {
        int id = (b - XBLK) * 256 + t;
        int which = id / (KK * CC * CC);
        int r = id % (KK * CC * CC);
        int k = r / (CC * CC);
        int rem = r % (CC * CC);
        int cin = rem / CC, cout = rem % CC;
        const float* W = which ? W2 : W1;
        unsigned short* Wt = which ? Wt2 : Wt1;
        Wt[k * CC * CC + cout * CC + cin] = f2bf(W[r]);
        return;
    }
    b -= XBLK + WBLK;
    for (int i = t; i < NB; i += 256) lc[i] = 0;
    __syncthreads();
    const int j0 = b * CHUNK;
    const int k  = j0 / NPTS;                  // CHUNK divides NPTS
    const i32x4* dsrc = (const i32x4*)(out_idx + j0);
    const i32x4* ssrc = (const i32x4*)(in_idx + j0);
    for (int ii = t; ii < CHUNK / 4; ii += 256) {
        i32x4 d = dsrc[ii];
#pragma unroll
        for (int q = 0; q < 4; ++q) atomicAdd(&lc[d[q] >> 7], 1);
    }
    __syncthreads();
    for (int i = t; i < NB; i += 256)
        lc[i] = atomicAdd(&cnt[k * NB + i], lc[i]);   // lc[i] := global base
    __syncthreads();
    for (int ii = t; ii < CHUNK / 4; ii += 256) {
        i32x4 d4 = dsrc[ii];
        i32x4 s4 = ssrc[ii];
#pragma unroll
        for (int q = 0; q < 4; ++q) {
            int d = d4[q];
            int bb = d >> 7;
            int pos = atomicAdd(&lc[bb], 1);
            if (pos < CAP)
                entries[(size_t)(k * NB + bb) * CAP + pos] =
                    ((unsigned)(d & 127) << 17) | (unsigned)s4[q];
        }
    }
}

// ---------------- r7-proven conv accumulate body (3-stage gather pipeline) ---------
__device__ __forceinline__ void conv_accum(
    const unsigned short* __restrict__ xsrc,   // [N][64] bf16 (xbf or a1)
    const unsigned short* __restrict__ Wt,     // [27][64][64] bf16
    const int* __restrict__ cnt,
    const unsigned* __restrict__ entries,
    int* ylds, const int blk,
    const int wave, const int quad, const int l16)
{
    const unsigned short* xq = xsrc + quad * 8;
    for (int k = wave; k < KK; k += 4) {
        const int bkt = k * NB + blk;
        const size_t start = (size_t)bkt * CAP;
        int E = cnt[bkt];
        E = E > CAP ? CAP : E;
        if (E == 0) continue;
        const int emax = E - 1;

        bf16x8 bfr[4][2];
        const unsigned short* wk = Wt + k * (CC * CC) + l16 * CC + quad * 8;
#pragma unroll
        for (int nt = 0; nt < 4; ++nt) {
            bfr[nt][0] = *(const bf16x8*)(wk + nt * 16 * CC);
            bfr[nt][1] = *(const bf16x8*)(wk + nt * 16 * CC + 32);
        }

        const int ntile = (E + 31) >> 5;

        unsigned eA0 = entries[start + min(l16, emax)];
        unsigned eB0 = entries[start + min(16 + l16, emax)];
        bf16x8 fc[2][2], fn[2][2];
        {
            const unsigned short* p0 = xq + (eA0 & 0x1FFFFu) * CC;
            const unsigned short* p1 = xq + (eB0 & 0x1FFFFu) * CC;
            fc[0][0] = *(const bf16x8*)p0;
            fc[0][1] = *(const bf16x8*)(p0 + 32);
            fc[1][0] = *(const bf16x8*)p1;
            fc[1][1] = *(const bf16x8*)(p1 + 32);
        }
        unsigned eA1 = entries[start + min(32 + l16, emax)];
        unsigned eB1 = entries[start + min(48 + l16, emax)];
        {
            const unsigned short* p0 = xq + (eA1 & 0x1FFFFu) * CC;
            const unsigned short* p1 = xq + (eB1 & 0x1FFFFu) * CC;
            fn[0][0] = *(const bf16x8*)p0;
            fn[0][1] = *(const bf16x8*)(p0 + 32);
            fn[1][0] = *(const bf16x8*)p1;
            fn[1][1] = *(const bf16x8*)(p1 + 32);
        }
        unsigned eA2 = entries[start + min(64 + l16, emax)];
        unsigned eB2 = entries[start + min(80 + l16, emax)];

        for (int t = 0; t < ntile; ++t) {
            const int tb = t * 32;
            unsigned dp[2][4];
#pragma unroll
            for (int rr = 0; rr < 4; ++rr) {
                dp[0][rr] = (unsigned)__shfl((int)eA0, quad * 4 + rr, 16);
                dp[1][rr] = (unsigned)__shfl((int)eB0, quad * 4 + rr, 16);
            }
            bf16x8 fp[2][2];
            {
                const unsigned short* p0 = xq + (eA2 & 0x1FFFFu) * CC;
                const unsigned short* p1 = xq + (eB2 & 0x1FFFFu) * CC;
                fp[0][0] = *(const bf16x8*)p0;
                fp[0][1] = *(const bf16x8*)(p0 + 32);
                fp[1][0] = *(const bf16x8*)p1;
                fp[1][1] = *(const bf16x8*)(p1 + 32);
            }
            unsigned eA3 = entries[start + min(tb + 96 + l16, emax)];
            unsigned eB3 = entries[start + min(tb + 112 + l16, emax)];

            f32x4 acc[2][4];
#pragma unroll
            for (int mt = 0; mt < 2; ++mt)
#pragma unroll
                for (int nt = 0; nt < 4; ++nt) acc[mt][nt] = (f32x4){0.f, 0.f, 0.f, 0.f};
            __builtin_amdgcn_s_setprio(1);
#pragma unroll
            for (int mt = 0; mt < 2; ++mt)
#pragma unroll
                for (int nt = 0; nt < 4; ++nt) {
                    acc[mt][nt] = __builtin_amdgcn_mfma_f32_16x16x32_bf16(
                        fc[mt][0], bfr[nt][0], acc[mt][nt], 0, 0, 0);
                    acc[mt][nt] = __builtin_amdgcn_mfma_f32_16x16x32_bf16(
                        fc[mt][1], bfr[nt][1], acc[mt][nt], 0, 0, 0);
                }
            __builtin_amdgcn_s_setprio(0);

#pragma unroll
            for (int mt = 0; mt < 2; ++mt)
#pragma unroll
                for (int rr = 0; rr < 4; ++rr) {
                    int slot = tb + mt * 16 + quad * 4 + rr;
                    if (slot < E) {
                        int row = (int)(dp[mt][rr] >> 17);
                        int xv = (row & 1) << 4;
                        unsigned* yp = (unsigned*)&ylds[row * 64 + l16];
                        atomicAdd(yp + (0 ^ xv),  (unsigned)f2fix(acc[mt][0][rr]));
                        atomicAdd(yp + (16 ^ xv), (unsigned)f2fix(acc[mt][1][rr]));
                        atomicAdd(yp + (32 ^ xv), (unsigned)f2fix(acc[mt][2][rr]));
                        atomicAdd(yp + (48 ^ xv), (unsigned)f2fix(acc[mt][3][rr]));
                    }
                }
            fc[0][0] = fn[0][0]; fc[0][1] = fn[0][1];
            fc[1][0] = fn[1][0]; fc[1][1] = fn[1][1];
            fn[0][0] = fp[0][0]; fn[0][1] = fp[0][1];
            fn[1][0] = fp[1][0]; fn[1][1] = fp[1][1];
            eA0 = eA1; eB0 = eB1;
            eA1 = eA2; eB1 = eB2;
            eA2 = eA3; eB2 = eB3;
        }
    }
}

// hand-rolled grid barrier: all NB blocks co-resident BY CONSTRUCTION
// (launch_bounds(256,4): VGPR<=128, LDS 34.8KB -> 4 blocks/CU x 256 CU = 1024 >= 782).
// R10 LESSON: spinning on an ACQUIRE agent load emits a cache-invalidate per
// iteration -> continuous whole-XCD L2 invalidation while co-resident blocks still
// compute (3.7x slowdown). Spin RELAXED (same load, no inv), then ONE acquire
// fence (__threadfence) after the spin exits.
__device__ __forceinline__ void grid_bar(unsigned* bar, unsigned target) {
    __syncthreads();
    if (threadIdx.x == 0) {
        __threadfence();   // release: flush this block's writes
        __hip_atomic_fetch_add(bar, 1u, __ATOMIC_RELEASE, __HIP_MEMORY_SCOPE_AGENT);
        while (__hip_atomic_load(bar, __ATOMIC_RELAXED, __HIP_MEMORY_SCOPE_AGENT) < target)
            __builtin_amdgcn_s_sleep(16);
        __threadfence();   // single acquire point: invalidate L1/L2 once
    }
    __syncthreads();
}

// ---------------- mega: conv1 -> BN1+ReLU -> conv2 -> BN2 + residual --------------
// y lives entirely in LDS (never hits HBM); a1 goes through a FRESH global buffer
// (no stale clean lines in remote L2s); cross-XCD handoff fenced via grid_bar.
__global__ __launch_bounds__(256, 4) void k_mega(
    const unsigned short* __restrict__ xb,    // [N][64] bf16
    const unsigned short* __restrict__ Wt1,
    const unsigned short* __restrict__ Wt2,
    const int* __restrict__ cnt,
    const unsigned* __restrict__ entries,
    unsigned short* __restrict__ a1,          // [N][64] bf16 (fresh buffer)
    const float* __restrict__ x,
    const float* __restrict__ gamma1, const float* __restrict__ beta1,
    const float* __restrict__ gamma2, const float* __restrict__ beta2,
    float* __restrict__ sums,                 // [256]: L1 sum/sumsq, L2 sum/sumsq
    unsigned* __restrict__ bar,               // [3] barrier counters (zeroed)
    float* __restrict__ out)
{
    __shared__ int   ylds[MT * 64];           // 32768 B
    __shared__ float ssum[2][4][64];          // 2048 B

    const int tid  = threadIdx.x;
    const int lane = tid & 63;
    const int wave = tid >> 6;                // 0..3
    const int quad = lane >> 4;
    const int l16  = lane & 15;
    const int blk  = blockIdx.x;
    const int i0   = blk << 7;
    const int col  = tid & 63;
    const int rg   = tid >> 6;                // 0..3 -> 32 rows each

    for (int i = tid; i < MT * 64; i += 256) ylds[i] = 0;
    __syncthreads();

    // ---- layer 1 conv ----
    conv_accum(xb, Wt1, cnt, entries, ylds, blk, wave, quad, l16);
    __syncthreads();

    // ---- BN1 stats (keep ylds intact) ----
    {
        float s = 0.f, q = 0.f;
#pragma unroll
        for (int i = 0; i < 32; ++i) {
            int row = rg * 32 + i;
            float v = (float)ylds[row * 64 + (col ^ ((row & 1) << 4))] * FPINV;
            s += v; q += v * v;        // rows >= NPTS are zero -> harmless
        }
        ssum[0][rg][col] = s;
        ssum[1][rg][col] = q;
        __syncthreads();
        if (tid < 128) {
            int which = tid >> 6, c = tid & 63;
            float a = ssum[which][0][c] + ssum[which][1][c] +
                      ssum[which][2][c] + ssum[which][3][c];
            atomicAdd(&sums[which * 64 + c], a);
        }
    }
    grid_bar(&bar[0], NB);

    // ---- BN1 finalize + ReLU -> a1 (bf16); zero ylds for conv2 ----
    {
        float su = __hip_atomic_load(&sums[col],      __ATOMIC_RELAXED, __HIP_MEMORY_SCOPE_AGENT);
        float sq = __hip_atomic_load(&sums[64 + col], __ATOMIC_RELAXED, __HIP_MEMORY_SCOPE_AGENT);
        float mu  = su * (1.0f / NPTS);
        float var = sq * (1.0f / NPTS) - mu * mu;
        float sc = gamma1[col] * rsqrtf(var + EPSBN);
        float bi = beta1[col] - mu * sc;
#pragma unroll
        for (int i = 0; i < 32; ++i) {
            int row = rg * 32 + i;
            int idx = row * 64 + (col ^ ((row & 1) << 4));
            float v = (float)ylds[idx] * FPINV;
            float r = fmaxf(fmaf(v, sc, bi), 0.f);
            int gr = i0 + row;
            if (gr < NPTS) a1[(long)gr * CC + col] = f2bf(r);
            ylds[idx] = 0;
        }
    }
    grid_bar(&bar[1], NB);                    // a1 visible device-wide

    // ---- layer 2 conv (gather a1) ----
    conv_accum(a1, Wt2, cnt, entries, ylds, blk, wave, quad, l16);
    __syncthreads();

    // ---- BN2 stats ----
    {
        float s = 0.f, q = 0.f;
#pragma unroll
        for (int i = 0; i < 32; ++i) {
            int row = rg * 32 + i;
            float v = (float)ylds[row * 64 + (col ^ ((row & 1) << 4))] * FPINV;
            s += v; q += v * v;
        }
        ssum[0][rg][col] = s;
        ssum[1][rg][col] = q;
        __syncthreads();
        if (tid < 128) {
            int which = tid >> 6, c = tid & 63;
            float a = ssum[which][0][c] + ssum[which][1][c] +
                      ssum[which][2][c] + ssum[which][3][c];
            atomicAdd(&sums[128 + which * 64 + c], a);
        }
    }
    grid_bar(&bar[2], NB);

    // ---- BN2 finalize + residual + ReLU -> out ----
    {
        float su = __hip_atomic_load(&sums[128 + col], __ATOMIC_RELAXED, __HIP_MEMORY_SCOPE_AGENT);
        float sq = __hip_atomic_load(&sums[192 + col], __ATOMIC_RELAXED, __HIP_MEMORY_SCOPE_AGENT);
        float mu  = su * (1.0f / NPTS);
        float var = sq * (1.0f / NPTS) - mu * mu;
        float sc = gamma2[col] * rsqrtf(var + EPSBN);
        float bi = beta2[col] - mu * sc;
#pragma unroll
        for (int i = 0; i < 32; ++i) {
            int row = rg * 32 + i;
            float v = (float)ylds[row * 64 + (col ^ ((row & 1) << 4))] * FPINV;
            int gr = i0 + row;
            if (gr < NPTS) {
                float xv = x[(long)gr * CC + col];
                out[(long)gr * CC + col] = fmaxf(fmaf(v, sc, bi) + xv, 0.f);
            }
        }
    }
}

extern "C" void kernel_launch(void* const* d_in, const int* in_sizes, int n_in,
                              void* d_out, int out_size, void* d_ws, size_t ws_size,
                              hipStream_t stream) {
    const float* x      = (const float*)d_in[0];
    // d_in[1] = norm_points (unused by the reference math)
    const float* W1     = (const float*)d_in[2];
    const float* gamma1 = (const float*)d_in[3];
    const float* beta1  = (const float*)d_in[4];
    const float* W2     = (const float*)d_in[5];
    const float* gamma2 = (const float*)d_in[6];
    const float* beta2  = (const float*)d_in[7];
    const int* in_idx   = (const int*)d_in[8];
    const int* out_idx  = (const int*)d_in[9];
    float* out = (float*)d_out;

    char* w = (char*)d_ws;
    size_t off = 0;
    auto alloc = [&](size_t bytes) -> char* {
        off = (off + 255) & ~(size_t)255;
        char* p = w + off;
        off += bytes;
        return p;
    };
    int*      cnt  = (int*)     alloc((size_t)KK * NB * 4);
    unsigned* bar  = (unsigned*)alloc(3 * 4);
    float*    sums = (float*)   alloc(256 * 4);   // [0:128) L1, [128:256) L2
    unsigned* entries = (unsigned*)alloc((size_t)KK * NB * CAP * 4);
    unsigned short* xbf = (unsigned short*)alloc((size_t)NPTS * CC * 2);
    unsigned short* a1  = (unsigned short*)alloc((size_t)NPTS * CC * 2);
    unsigned short* Wt1 = (unsigned short*)alloc((size_t)KK * CC * CC * 2);
    unsigned short* Wt2 = (unsigned short*)alloc((size_t)KK * CC * CC * 2);

    // zero cnt + bar + sums in one shot (contiguous incl. alignment gaps)
    size_t zlen = (size_t)((char*)(sums + 256) - (char*)cnt);
    hipMemsetAsync(cnt, 0, zlen, stream);

    k_prep_part<<<XBLK + WBLK + NCH, 256, 0, stream>>>(
        x, W1, W2, out_idx, in_idx, xbf, Wt1, Wt2, cnt, entries);

    k_mega<<<NB, 256, 0, stream>>>(
        xbf, Wt1, Wt2, cnt, entries, a1, x,
        gamma1, beta1, gamma2, beta2, sums, bar, out);
}

// Round 12
// 418.096 us; speedup vs baseline: 2.6726x; 2.0065x over previous
//
#include <hip/hip_runtime.h>

#define NPTS 100000
#define CC   64
#define KK   27
#define TOT  (KK * NPTS)        // 2,700,000 edges
#define EPSBN 1e-5f
#define MT   128                // dst rows per conv block
#define NB   ((NPTS + MT - 1) / MT)   // 782 dst-blocks (= buckets per k)
#define CAP  200                // bucket capacity: Poisson(128) + 6.4 sigma

#define CHUNK  12500            // edges per partition block (divides NPTS)
#define NCH    (TOT / CHUNK)    // 216 chunks total

#define XBLK   (NPTS * CC / 1024)       // 6250 blocks for x conversion
#define WBLK   (2 * KK * CC * CC / 256) // 864 blocks for W prep

// fixed-point scale for the LDS integer accumulator (ds_add_u32 is native;
// fp32 LDS atomicAdd compiles to a CAS retry loop -> 7x slowdown, round 1)
#define FPSCALE 262144.0f               // 2^18
#define FPINV   3.814697265625e-06f     // 2^-18
#define FPMAGIC 12582912.0f             // 1.5 * 2^23
#define FPBITS  0x4B400000

typedef float          f32x4  __attribute__((ext_vector_type(4)));
typedef short          bf16x8 __attribute__((ext_vector_type(8)));
typedef unsigned int   u32x4  __attribute__((ext_vector_type(4)));
typedef unsigned short u16x4  __attribute__((ext_vector_type(4)));
typedef int            i32x4  __attribute__((ext_vector_type(4)));

__device__ __forceinline__ unsigned short f2bf(float f) {
    unsigned int u = __float_as_uint(f);
    u = (u + 0x7fffu + ((u >> 16) & 1u)) >> 16;
    return (unsigned short)u;
}

__device__ __forceinline__ int f2fix(float v) {
    return __float_as_int(fmaf(v, FPSCALE, FPMAGIC)) - FPBITS;
}

// ------------- fused prep (x->bf16, W->Wt) + single-pass CSR partition ------------
__global__ __launch_bounds__(256) void k_prep_part(
    const float* __restrict__ x,
    const float* __restrict__ W1, const float* __restrict__ W2,
    const int* __restrict__ out_idx, const int* __restrict__ in_idx,
    unsigned short* __restrict__ xb,
    unsigned short* __restrict__ Wt1, unsigned short* __restrict__ Wt2,
    int* __restrict__ cnt, unsigned* __restrict__ entries) {
    __shared__ int lc[NB];
    const int t = threadIdx.x;
    int b = blockIdx.x;
    if (b < XBLK) {
        int id = b * 256 + t;
        f32x4 v = ((const f32x4*)x)[id];
        u16x4 o;
#pragma unroll
        for (int j = 0; j < 4; ++j) o[j] = f2bf(v[j]);
        ((u16x4*)xb)[id] = o;
        return;
    }
    if (b < XBLK + WBLK) {
        int id = (b - XBLK) * 256 + t;
        int which = id / (KK * CC * CC);
        int r = id % (KK * CC * CC);
        int k = r / (CC * CC);
        int rem = r % (CC * CC);
        int cin = rem / CC, cout = rem % CC;
        const float* W = which ? W2 : W1;
        unsigned short* Wt = which ? Wt2 : Wt1;
        Wt[k * CC * CC + cout * CC + cin] = f2bf(W[r]);
        return;
    }
    b -= XBLK + WBLK;
    for (int i = t; i < NB; i += 256) lc[i] = 0;
    __syncthreads();
    const int j0 = b * CHUNK;
    const int k  = j0 / NPTS;                  // CHUNK divides NPTS
    const i32x4* dsrc = (const i32x4*)(out_idx + j0);
    const i32x4* ssrc = (const i32x4*)(in_idx + j0);
    for (int ii = t; ii < CHUNK / 4; ii += 256) {
        i32x4 d = dsrc[ii];
#pragma unroll
        for (int q = 0; q < 4; ++q) atomicAdd(&lc[d[q] >> 7], 1);
    }
    __syncthreads();
    for (int i = t; i < NB; i += 256)
        lc[i] = atomicAdd(&cnt[k * NB + i], lc[i]);   // lc[i] := global base
    __syncthreads();
    for (int ii = t; ii < CHUNK / 4; ii += 256) {
        i32x4 d4 = dsrc[ii];
        i32x4 s4 = ssrc[ii];
#pragma unroll
        for (int q = 0; q < 4; ++q) {
            int d = d4[q];
            int bb = d >> 7;
            int pos = atomicAdd(&lc[bb], 1);
            if (pos < CAP)
                entries[(size_t)(k * NB + bb) * CAP + pos] =
                    ((unsigned)(d & 127) << 17) | (unsigned)s4[q];
        }
    }
}

// ---------------- conv: round-7 body verbatim (109 us best measured) ---------------
// 512 threads = 8 waves/block; wave w handles k = w, w+8, ...
// 3-stage gather pipeline; scatter rows from eg regs via width-16 shuffles.
// launch_bounds(512,4): VGPR cap 128. NEVER request waves/EU the allocator can't
// meet: (256,5)->48 VGPR/140MB scratch (r3); (512,6)->40 VGPR/1.4GB scratch (r5).
__global__ __launch_bounds__(512, 4) void k_conv(
    const unsigned short* __restrict__ xb,    // [N][64] bf16
    const unsigned short* __restrict__ Wt,    // [27][cout=64][cin=64] bf16
    const int* __restrict__ cnt,              // [KK*NB] bucket counts
    const unsigned* __restrict__ entries,     // [KK*NB*CAP]: (dloc7<<17)|src17
    float* __restrict__ y,                    // [N][64] fp32
    float* __restrict__ sums)                 // [128]: sum, sumsq per channel
{
    __shared__ int ylds[MT * 64];             // 32768 B

    const int tid  = threadIdx.x;
    const int lane = tid & 63;
    const int wave = tid >> 6;                // 0..7
    const int quad = lane >> 4;
    const int l16  = lane & 15;
    const int blk  = blockIdx.x;
    const int i0   = blk << 7;

    for (int i = tid; i < MT * 64; i += 512) ylds[i] = 0;
    __syncthreads();

    const unsigned short* xq = xb + quad * 8;

    for (int k = wave; k < KK; k += 8) {
        const int bkt   = k * NB + blk;
        const size_t start = (size_t)bkt * CAP;
        int E = cnt[bkt];
        E = E > CAP ? CAP : E;
        if (E == 0) continue;
        const int emax = E - 1;

        // B fragments straight from global Wt (221 KB total, L2-hot)
        bf16x8 bfr[4][2];
        const unsigned short* wk = Wt + k * (CC * CC) + l16 * CC + quad * 8;
#pragma unroll
        for (int nt = 0; nt < 4; ++nt) {
            bfr[nt][0] = *(const bf16x8*)(wk + nt * 16 * CC);
            bfr[nt][1] = *(const bf16x8*)(wk + nt * 16 * CC + 32);
        }

        const int ntile = (E + 31) >> 5;

        // ---- pipeline prologue: eg queue 4 deep, fragments 3 deep ----
        unsigned eA0 = entries[start + min(l16, emax)];
        unsigned eB0 = entries[start + min(16 + l16, emax)];
        bf16x8 fc[2][2], fn[2][2];
        {
            const unsigned short* p0 = xq + (eA0 & 0x1FFFFu) * CC;
            const unsigned short* p1 = xq + (eB0 & 0x1FFFFu) * CC;
            fc[0][0] = *(const bf16x8*)p0;
            fc[0][1] = *(const bf16x8*)(p0 + 32);
            fc[1][0] = *(const bf16x8*)p1;
            fc[1][1] = *(const bf16x8*)(p1 + 32);
        }
        unsigned eA1 = entries[start + min(32 + l16, emax)];
        unsigned eB1 = entries[start + min(48 + l16, emax)];
        {
            const unsigned short* p0 = xq + (eA1 & 0x1FFFFu) * CC;
            const unsigned short* p1 = xq + (eB1 & 0x1FFFFu) * CC;
            fn[0][0] = *(const bf16x8*)p0;
            fn[0][1] = *(const bf16x8*)(p0 + 32);
            fn[1][0] = *(const bf16x8*)p1;
            fn[1][1] = *(const bf16x8*)(p1 + 32);
        }
        unsigned eA2 = entries[start + min(64 + l16, emax)];
        unsigned eB2 = entries[start + min(80 + l16, emax)];

        for (int t = 0; t < ntile; ++t) {
            const int tb = t * 32;
            // scatter rows for THIS tile from resident eg regs (width-16 shuffle)
            unsigned dp[2][4];
#pragma unroll
            for (int rr = 0; rr < 4; ++rr) {
                dp[0][rr] = (unsigned)__shfl((int)eA0, quad * 4 + rr, 16);
                dp[1][rr] = (unsigned)__shfl((int)eB0, quad * 4 + rr, 16);
            }
            // issue gather for tile t+2 from resident indices
            bf16x8 fp[2][2];
            {
                const unsigned short* p0 = xq + (eA2 & 0x1FFFFu) * CC;
                const unsigned short* p1 = xq + (eB2 & 0x1FFFFu) * CC;
                fp[0][0] = *(const bf16x8*)p0;
                fp[0][1] = *(const bf16x8*)(p0 + 32);
                fp[1][0] = *(const bf16x8*)p1;
                fp[1][1] = *(const bf16x8*)(p1 + 32);
            }
            // prefetch indices for tile t+3
            unsigned eA3 = entries[start + min(tb + 96 + l16, emax)];
            unsigned eB3 = entries[start + min(tb + 112 + l16, emax)];

            f32x4 acc[2][4];
#pragma unroll
            for (int mt = 0; mt < 2; ++mt)
#pragma unroll
                for (int nt = 0; nt < 4; ++nt) acc[mt][nt] = (f32x4){0.f, 0.f, 0.f, 0.f};
            __builtin_amdgcn_s_setprio(1);
#pragma unroll
            for (int mt = 0; mt < 2; ++mt)
#pragma unroll
                for (int nt = 0; nt < 4; ++nt) {
                    acc[mt][nt] = __builtin_amdgcn_mfma_f32_16x16x32_bf16(
                        fc[mt][0], bfr[nt][0], acc[mt][nt], 0, 0, 0);
                    acc[mt][nt] = __builtin_amdgcn_mfma_f32_16x16x32_bf16(
                        fc[mt][1], bfr[nt][1], acc[mt][nt], 0, 0, 0);
                }
            __builtin_amdgcn_s_setprio(0);

            // scatter: 32 native ds_add_u32 per lane per tile (fixed-point, swizzled)
#pragma unroll
            for (int mt = 0; mt < 2; ++mt)
#pragma unroll
                for (int rr = 0; rr < 4; ++rr) {
                    int slot = tb + mt * 16 + quad * 4 + rr;
                    if (slot < E) {
                        int row = (int)(dp[mt][rr] >> 17);
                        int xv = (row & 1) << 4;
                        unsigned* yp = (unsigned*)&ylds[row * 64 + l16];
                        atomicAdd(yp + (0 ^ xv),  (unsigned)f2fix(acc[mt][0][rr]));
                        atomicAdd(yp + (16 ^ xv), (unsigned)f2fix(acc[mt][1][rr]));
                        atomicAdd(yp + (32 ^ xv), (unsigned)f2fix(acc[mt][2][rr]));
                        atomicAdd(yp + (48 ^ xv), (unsigned)f2fix(acc[mt][3][rr]));
                    }
                }
            // rotate pipeline
            fc[0][0] = fn[0][0]; fc[0][1] = fn[0][1];
            fc[1][0] = fn[1][0]; fc[1][1] = fn[1][1];
            fn[0][0] = fp[0][0]; fn[0][1] = fp[0][1];
            fn[1][0] = fp[1][0]; fn[1][1] = fp[1][1];
            eA0 = eA1; eB0 = eB1;
            eA1 = eA2; eB1 = eB2;
            eA2 = eA3; eB2 = eB3;
        }
    }
    __syncthreads();

    // epilogue: write y + fused BN partial sums (ylds reused as scratch after reads)
    const int col = tid & 63;
    const int rg  = tid >> 6;                 // 0..7 -> 16 rows each
    float s = 0.f, q = 0.f;
#pragma unroll
    for (int i = 0; i < 16; ++i) {
        int row = rg * 16 + i;
        float v = (float)ylds[row * 64 + (col ^ ((row & 1) << 4))] * FPINV;
        int gr = i0 + row;
        if (gr < NPTS) y[(long)gr * CC + col] = v;
        s += v; q += v * v;
    }
    __syncthreads();                      // all ylds reads done
    float* ps = (float*)ylds;
    ps[rg * 128 + col] = s;
    ps[rg * 128 + 64 + col] = q;
    __syncthreads();
    if (tid < 128) {
        int which = tid >> 6, c = tid & 63;
        float a = 0.f;
#pragma unroll
        for (int wv = 0; wv < 8; ++wv) a += ps[wv * 128 + which * 64 + c];
        atomicAdd(&sums[which * 64 + c], a);
    }
}

// ---------------- a1 = bf16(relu(y*s + b)) with inline BN finalize ----------------
__global__ void k_apply(const float* __restrict__ y, const float* __restrict__ sums,
                        const float* __restrict__ gamma, const float* __restrict__ beta,
                        unsigned short* __restrict__ ab) {
    __shared__ float sb[128];
    int t = threadIdx.x;
    if (t < 64) {
        float mu  = sums[t] * (1.0f / NPTS);
        float var = sums[t + 64] * (1.0f / NPTS) - mu * mu;
        float s = gamma[t] * rsqrtf(var + EPSBN);
        sb[t] = s;
        sb[t + 64] = beta[t] - mu * s;
    }
    __syncthreads();
    int id = blockIdx.x * 256 + t;
    f32x4 v = ((const f32x4*)y)[id];
    int c0 = (id * 4) & 63;
    u16x4 o;
#pragma unroll
    for (int j = 0; j < 4; ++j) {
        float r = fmaxf(v[j] * sb[c0 + j] + sb[64 + c0 + j], 0.f);
        o[j] = f2bf(r);
    }
    ((u16x4*)ab)[id] = o;
}

// ---------------- out = relu(y*s + b + x) with inline BN finalize ----------------
__global__ void k_final(const float* __restrict__ y, const float* __restrict__ x,
                        const float* __restrict__ sums,
                        const float* __restrict__ gamma, const float* __restrict__ beta,
                        float* __restrict__ out) {
    __shared__ float sb[128];
    int t = threadIdx.x;
    if (t < 64) {
        float mu  = sums[t] * (1.0f / NPTS);
        float var = sums[t + 64] * (1.0f / NPTS) - mu * mu;
        float s = gamma[t] * rsqrtf(var + EPSBN);
        sb[t] = s;
        sb[t + 64] = beta[t] - mu * s;
    }
    __syncthreads();
    int id = blockIdx.x * 256 + t;
    f32x4 v  = ((const f32x4*)y)[id];
    f32x4 xv = ((const f32x4*)x)[id];
    int c0 = (id * 4) & 63;
    f32x4 o;
#pragma unroll
    for (int j = 0; j < 4; ++j)
        o[j] = fmaxf(v[j] * sb[c0 + j] + sb[64 + c0 + j] + xv[j], 0.f);
    ((f32x4*)out)[id] = o;
}

extern "C" void kernel_launch(void* const* d_in, const int* in_sizes, int n_in,
                              void* d_out, int out_size, void* d_ws, size_t ws_size,
                              hipStream_t stream) {
    const float* x      = (const float*)d_in[0];
    // d_in[1] = norm_points (unused by the reference math)
    const float* W1     = (const float*)d_in[2];
    const float* gamma1 = (const float*)d_in[3];
    const float* beta1  = (const float*)d_in[4];
    const float* W2     = (const float*)d_in[5];
    const float* gamma2 = (const float*)d_in[6];
    const float* beta2  = (const float*)d_in[7];
    const int* in_idx   = (const int*)d_in[8];
    const int* out_idx  = (const int*)d_in[9];
    float* out = (float*)d_out;

    char* w = (char*)d_ws;
    size_t off = 0;
    auto alloc = [&](size_t bytes) -> char* {
        off = (off + 255) & ~(size_t)255;
        char* p = w + off;
        off += bytes;
        return p;
    };
    int*   cnt       = (int*)     alloc((size_t)KK * NB * 4);
    float* sums      = (float*)   alloc(256 * 4);   // [0:128) layer1, [128:256) layer2
    unsigned* entries = (unsigned*)alloc((size_t)KK * NB * CAP * 4);
    unsigned short* xbf = (unsigned short*)alloc((size_t)NPTS * CC * 2);
    unsigned short* Wt1 = (unsigned short*)alloc((size_t)KK * CC * CC * 2);
    unsigned short* Wt2 = (unsigned short*)alloc((size_t)KK * CC * CC * 2);
    float* y = (float*)alloc((size_t)NPTS * CC * 4);

    // zero cnt + sums in one shot (contiguous allocations incl. alignment gap)
    size_t zlen = (size_t)((char*)(sums + 256) - (char*)cnt);
    hipMemsetAsync(cnt, 0, zlen, stream);

    k_prep_part<<<XBLK + WBLK + NCH, 256, 0, stream>>>(
        x, W1, W2, out_idx, in_idx, xbf, Wt1, Wt2, cnt, entries);

    k_conv<<<NB, 512, 0, stream>>>(xbf, Wt1, cnt, entries, y, sums);
    k_apply<<<NPTS * CC / 1024, 256, 0, stream>>>(y, sums, gamma1, beta1, xbf);  // a1 -> xbf
    k_conv<<<NB, 512, 0, stream>>>(xbf, Wt2, cnt, entries, y, sums + 128);
    k_final<<<NPTS * CC / 1024, 256, 0, stream>>>(y, x, sums + 128, gamma2, beta2, out);
}

// Round 13
// 376.415 us; speedup vs baseline: 2.9686x; 1.1107x over previous
//
#include <hip/hip_runtime.h>

#define NPTS 100000
#define CC   64
#define KK   27
#define TOT  (KK * NPTS)        // 2,700,000 edges
#define EPSBN 1e-5f
#define MT   128                // dst rows per conv block
#define NB   ((NPTS + MT - 1) / MT)   // 782 dst-blocks (= buckets per k)
#define CAP  200                // bucket capacity: Poisson(128) + 6.4 sigma

#define CHUNK  2500             // edges per partition block (divides NPTS; /4 exact)
#define NCH    (TOT / CHUNK)    // 1080 chunks total -> 4.2 blocks/CU (r12: 216 = 0.84/CU)

#define XBLK   (NPTS * CC / 1024)       // 6250 blocks for x conversion
#define WBLK   (2 * KK * CC * CC / 256) // 864 blocks for W prep

// fixed-point scale for the LDS integer accumulator (ds_add_u32 is native;
// fp32 LDS atomicAdd compiles to a CAS retry loop -> 7x slowdown, round 1)
#define FPSCALE 262144.0f               // 2^18
#define FPINV   3.814697265625e-06f     // 2^-18
#define FPMAGIC 12582912.0f             // 1.5 * 2^23
#define FPBITS  0x4B400000

typedef float          f32x4  __attribute__((ext_vector_type(4)));
typedef short          bf16x8 __attribute__((ext_vector_type(8)));
typedef unsigned int   u32x4  __attribute__((ext_vector_type(4)));
typedef unsigned short u16x4  __attribute__((ext_vector_type(4)));
typedef int            i32x4  __attribute__((ext_vector_type(4)));

__device__ __forceinline__ unsigned short f2bf(float f) {
    unsigned int u = __float_as_uint(f);
    u = (u + 0x7fffu + ((u >> 16) & 1u)) >> 16;
    return (unsigned short)u;
}

__device__ __forceinline__ int f2fix(float v) {
    return __float_as_int(fmaf(v, FPSCALE, FPMAGIC)) - FPBITS;
}

// ------------- fused prep (x->bf16, W->Wt) + single-pass CSR partition ------------
// Partition blocks FIRST (b < NCH): they are the long pole (scattered atomics);
// starting them at t=0 lets the 6250 streaming x-convert blocks fill in around them.
__global__ __launch_bounds__(256) void k_prep_part(
    const float* __restrict__ x,
    const float* __restrict__ W1, const float* __restrict__ W2,
    const int* __restrict__ out_idx, const int* __restrict__ in_idx,
    unsigned short* __restrict__ xb,
    unsigned short* __restrict__ Wt1, unsigned short* __restrict__ Wt2,
    int* __restrict__ cnt, unsigned* __restrict__ entries) {
    __shared__ int lc[NB];
    const int t = threadIdx.x;
    int b = blockIdx.x;
    if (b >= NCH) {
        b -= NCH;
        if (b < XBLK) {
            int id = b * 256 + t;
            f32x4 v = ((const f32x4*)x)[id];
            u16x4 o;
#pragma unroll
            for (int j = 0; j < 4; ++j) o[j] = f2bf(v[j]);
            ((u16x4*)xb)[id] = o;
        } else {
            int id = (b - XBLK) * 256 + t;
            int which = id / (KK * CC * CC);
            int r = id % (KK * CC * CC);
            int k = r / (CC * CC);
            int rem = r % (CC * CC);
            int cin = rem / CC, cout = rem % CC;
            const float* W = which ? W2 : W1;
            unsigned short* Wt = which ? Wt2 : Wt1;
            Wt[k * CC * CC + cout * CC + cin] = f2bf(W[r]);
        }
        return;
    }
    for (int i = t; i < NB; i += 256) lc[i] = 0;
    __syncthreads();
    const int j0 = b * CHUNK;
    const int k  = j0 / NPTS;                  // CHUNK divides NPTS
    const i32x4* dsrc = (const i32x4*)(out_idx + j0);
    const i32x4* ssrc = (const i32x4*)(in_idx + j0);
    for (int ii = t; ii < CHUNK / 4; ii += 256) {
        i32x4 d = dsrc[ii];
#pragma unroll
        for (int q = 0; q < 4; ++q) atomicAdd(&lc[d[q] >> 7], 1);
    }
    __syncthreads();
    for (int i = t; i < NB; i += 256)
        lc[i] = atomicAdd(&cnt[k * NB + i], lc[i]);   // lc[i] := global base
    __syncthreads();
    for (int ii = t; ii < CHUNK / 4; ii += 256) {
        i32x4 d4 = dsrc[ii];
        i32x4 s4 = ssrc[ii];
#pragma unroll
        for (int q = 0; q < 4; ++q) {
            int d = d4[q];
            int bb = d >> 7;
            int pos = atomicAdd(&lc[bb], 1);
            if (pos < CAP)
                entries[(size_t)(k * NB + bb) * CAP + pos] =
                    ((unsigned)(d & 127) << 17) | (unsigned)s4[q];
        }
    }
}

// ---------------- conv: round-7 body verbatim (109-118 us measured) ----------------
// 512 threads = 8 waves/block; wave w handles k = w, w+8, ...
// 3-stage gather pipeline; scatter rows from eg regs via width-16 shuffles.
// launch_bounds(512,4): VGPR cap 128. NEVER request waves/EU the allocator can't
// meet: (256,5)->48 VGPR/140MB scratch (r3); (512,6)->40 VGPR/1.4GB scratch (r5).
__global__ __launch_bounds__(512, 4) void k_conv(
    const unsigned short* __restrict__ xb,    // [N][64] bf16
    const unsigned short* __restrict__ Wt,    // [27][cout=64][cin=64] bf16
    const int* __restrict__ cnt,              // [KK*NB] bucket counts
    const unsigned* __restrict__ entries,     // [KK*NB*CAP]: (dloc7<<17)|src17
    float* __restrict__ y,                    // [N][64] fp32
    float* __restrict__ sums)                 // [128]: sum, sumsq per channel
{
    __shared__ int ylds[MT * 64];             // 32768 B

    const int tid  = threadIdx.x;
    const int lane = tid & 63;
    const int wave = tid >> 6;                // 0..7
    const int quad = lane >> 4;
    const int l16  = lane & 15;
    const int blk  = blockIdx.x;
    const int i0   = blk << 7;

    for (int i = tid; i < MT * 64; i += 512) ylds[i] = 0;
    __syncthreads();

    const unsigned short* xq = xb + quad * 8;

    for (int k = wave; k < KK; k += 8) {
        const int bkt   = k * NB + blk;
        const size_t start = (size_t)bkt * CAP;
        int E = cnt[bkt];
        E = E > CAP ? CAP : E;
        if (E == 0) continue;
        const int emax = E - 1;

        // B fragments straight from global Wt (221 KB total, L2-hot)
        bf16x8 bfr[4][2];
        const unsigned short* wk = Wt + k * (CC * CC) + l16 * CC + quad * 8;
#pragma unroll
        for (int nt = 0; nt < 4; ++nt) {
            bfr[nt][0] = *(const bf16x8*)(wk + nt * 16 * CC);
            bfr[nt][1] = *(const bf16x8*)(wk + nt * 16 * CC + 32);
        }

        const int ntile = (E + 31) >> 5;

        // ---- pipeline prologue: eg queue 4 deep, fragments 3 deep ----
        unsigned eA0 = entries[start + min(l16, emax)];
        unsigned eB0 = entries[start + min(16 + l16, emax)];
        bf16x8 fc[2][2], fn[2][2];
        {
            const unsigned short* p0 = xq + (eA0 & 0x1FFFFu) * CC;
            const unsigned short* p1 = xq + (eB0 & 0x1FFFFu) * CC;
            fc[0][0] = *(const bf16x8*)p0;
            fc[0][1] = *(const bf16x8*)(p0 + 32);
            fc[1][0] = *(const bf16x8*)p1;
            fc[1][1] = *(const bf16x8*)(p1 + 32);
        }
        unsigned eA1 = entries[start + min(32 + l16, emax)];
        unsigned eB1 = entries[start + min(48 + l16, emax)];
        {
            const unsigned short* p0 = xq + (eA1 & 0x1FFFFu) * CC;
            const unsigned short* p1 = xq + (eB1 & 0x1FFFFu) * CC;
            fn[0][0] = *(const bf16x8*)p0;
            fn[0][1] = *(const bf16x8*)(p0 + 32);
            fn[1][0] = *(const bf16x8*)p1;
            fn[1][1] = *(const bf16x8*)(p1 + 32);
        }
        unsigned eA2 = entries[start + min(64 + l16, emax)];
        unsigned eB2 = entries[start + min(80 + l16, emax)];

        for (int t = 0; t < ntile; ++t) {
            const int tb = t * 32;
            // scatter rows for THIS tile from resident eg regs (width-16 shuffle)
            unsigned dp[2][4];
#pragma unroll
            for (int rr = 0; rr < 4; ++rr) {
                dp[0][rr] = (unsigned)__shfl((int)eA0, quad * 4 + rr, 16);
                dp[1][rr] = (unsigned)__shfl((int)eB0, quad * 4 + rr, 16);
            }
            // issue gather for tile t+2 from resident indices
            bf16x8 fp[2][2];
            {
                const unsigned short* p0 = xq + (eA2 & 0x1FFFFu) * CC;
                const unsigned short* p1 = xq + (eB2 & 0x1FFFFu) * CC;
                fp[0][0] = *(const bf16x8*)p0;
                fp[0][1] = *(const bf16x8*)(p0 + 32);
                fp[1][0] = *(const bf16x8*)p1;
                fp[1][1] = *(const bf16x8*)(p1 + 32);
            }
            // prefetch indices for tile t+3
            unsigned eA3 = entries[start + min(tb + 96 + l16, emax)];
            unsigned eB3 = entries[start + min(tb + 112 + l16, emax)];

            f32x4 acc[2][4];
#pragma unroll
            for (int mt = 0; mt < 2; ++mt)
#pragma unroll
                for (int nt = 0; nt < 4; ++nt) acc[mt][nt] = (f32x4){0.f, 0.f, 0.f, 0.f};
            __builtin_amdgcn_s_setprio(1);
#pragma unroll
            for (int mt = 0; mt < 2; ++mt)
#pragma unroll
                for (int nt = 0; nt < 4; ++nt) {
                    acc[mt][nt] = __builtin_amdgcn_mfma_f32_16x16x32_bf16(
                        fc[mt][0], bfr[nt][0], acc[mt][nt], 0, 0, 0);
                    acc[mt][nt] = __builtin_amdgcn_mfma_f32_16x16x32_bf16(
                        fc[mt][1], bfr[nt][1], acc[mt][nt], 0, 0, 0);
                }
            __builtin_amdgcn_s_setprio(0);

            // scatter: 32 native ds_add_u32 per lane per tile (fixed-point, swizzled)
#pragma unroll
            for (int mt = 0; mt < 2; ++mt)
#pragma unroll
                for (int rr = 0; rr < 4; ++rr) {
                    int slot = tb + mt * 16 + quad * 4 + rr;
                    if (slot < E) {
                        int row = (int)(dp[mt][rr] >> 17);
                        int xv = (row & 1) << 4;
                        unsigned* yp = (unsigned*)&ylds[row * 64 + l16];
                        atomicAdd(yp + (0 ^ xv),  (unsigned)f2fix(acc[mt][0][rr]));
                        atomicAdd(yp + (16 ^ xv), (unsigned)f2fix(acc[mt][1][rr]));
                        atomicAdd(yp + (32 ^ xv), (unsigned)f2fix(acc[mt][2][rr]));
                        atomicAdd(yp + (48 ^ xv), (unsigned)f2fix(acc[mt][3][rr]));
                    }
                }
            // rotate pipeline
            fc[0][0] = fn[0][0]; fc[0][1] = fn[0][1];
            fc[1][0] = fn[1][0]; fc[1][1] = fn[1][1];
            fn[0][0] = fp[0][0]; fn[0][1] = fp[0][1];
            fn[1][0] = fp[1][0]; fn[1][1] = fp[1][1];
            eA0 = eA1; eB0 = eB1;
            eA1 = eA2; eB1 = eB2;
            eA2 = eA3; eB2 = eB3;
        }
    }
    __syncthreads();

    // epilogue: write y + fused BN partial sums (ylds reused as scratch after reads)
    const int col = tid & 63;
    const int rg  = tid >> 6;                 // 0..7 -> 16 rows each
    float s = 0.f, q = 0.f;
#pragma unroll
    for (int i = 0; i < 16; ++i) {
        int row = rg * 16 + i;
        float v = (float)ylds[row * 64 + (col ^ ((row & 1) << 4))] * FPINV;
        int gr = i0 + row;
        if (gr < NPTS) y[(long)gr * CC + col] = v;
        s += v; q += v * v;
    }
    __syncthreads();                      // all ylds reads done
    float* ps = (float*)ylds;
    ps[rg * 128 + col] = s;
    ps[rg * 128 + 64 + col] = q;
    __syncthreads();
    if (tid < 128) {
        int which = tid >> 6, c = tid & 63;
        float a = 0.f;
#pragma unroll
        for (int wv = 0; wv < 8; ++wv) a += ps[wv * 128 + which * 64 + c];
        atomicAdd(&sums[which * 64 + c], a);
    }
}

// ---------------- a1 = bf16(relu(y*s + b)) with inline BN finalize ----------------
__global__ void k_apply(const float* __restrict__ y, const float* __restrict__ sums,
                        const float* __restrict__ gamma, const float* __restrict__ beta,
                        unsigned short* __restrict__ ab) {
    __shared__ float sb[128];
    int t = threadIdx.x;
    if (t < 64) {
        float mu  = sums[t] * (1.0f / NPTS);
        float var = sums[t + 64] * (1.0f / NPTS) - mu * mu;
        float s = gamma[t] * rsqrtf(var + EPSBN);
        sb[t] = s;
        sb[t + 64] = beta[t] - mu * s;
    }
    __syncthreads();
    int id = blockIdx.x * 256 + t;
    f32x4 v = ((const f32x4*)y)[id];
    int c0 = (id * 4) & 63;
    u16x4 o;
#pragma unroll
    for (int j = 0; j < 4; ++j) {
        float r = fmaxf(v[j] * sb[c0 + j] + sb[64 + c0 + j], 0.f);
        o[j] = f2bf(r);
    }
    ((u16x4*)ab)[id] = o;
}

// ---------------- out = relu(y*s + b + x) with inline BN finalize ----------------
__global__ void k_final(const float* __restrict__ y, const float* __restrict__ x,
                        const float* __restrict__ sums,
                        const float* __restrict__ gamma, const float* __restrict__ beta,
                        float* __restrict__ out) {
    __shared__ float sb[128];
    int t = threadIdx.x;
    if (t < 64) {
        float mu  = sums[t] * (1.0f / NPTS);
        float var = sums[t + 64] * (1.0f / NPTS) - mu * mu;
        float s = gamma[t] * rsqrtf(var + EPSBN);
        sb[t] = s;
        sb[t + 64] = beta[t] - mu * s;
    }
    __syncthreads();
    int id = blockIdx.x * 256 + t;
    f32x4 v  = ((const f32x4*)y)[id];
    f32x4 xv = ((const f32x4*)x)[id];
    int c0 = (id * 4) & 63;
    f32x4 o;
#pragma unroll
    for (int j = 0; j < 4; ++j)
        o[j] = fmaxf(v[j] * sb[c0 + j] + sb[64 + c0 + j] + xv[j], 0.f);
    ((f32x4*)out)[id] = o;
}

extern "C" void kernel_launch(void* const* d_in, const int* in_sizes, int n_in,
                              void* d_out, int out_size, void* d_ws, size_t ws_size,
                              hipStream_t stream) {
    const float* x      = (const float*)d_in[0];
    // d_in[1] = norm_points (unused by the reference math)
    const float* W1     = (const float*)d_in[2];
    const float* gamma1 = (const float*)d_in[3];
    const float* beta1  = (const float*)d_in[4];
    const float* W2     = (const float*)d_in[5];
    const float* gamma2 = (const float*)d_in[6];
    const float* beta2  = (const float*)d_in[7];
    const int* in_idx   = (const int*)d_in[8];
    const int* out_idx  = (const int*)d_in[9];
    float* out = (float*)d_out;

    char* w = (char*)d_ws;
    size_t off = 0;
    auto alloc = [&](size_t bytes) -> char* {
        off = (off + 255) & ~(size_t)255;
        char* p = w + off;
        off += bytes;
        return p;
    };
    int*   cnt       = (int*)     alloc((size_t)KK * NB * 4);
    float* sums      = (float*)   alloc(256 * 4);   // [0:128) layer1, [128:256) layer2
    unsigned* entries = (unsigned*)alloc((size_t)KK * NB * CAP * 4);
    unsigned short* xbf = (unsigned short*)alloc((size_t)NPTS * CC * 2);
    unsigned short* Wt1 = (unsigned short*)alloc((size_t)KK * CC * CC * 2);
    unsigned short* Wt2 = (unsigned short*)alloc((size_t)KK * CC * CC * 2);
    float* y = (float*)alloc((size_t)NPTS * CC * 4);

    // zero cnt + sums in one shot (contiguous allocations incl. alignment gap)
    size_t zlen = (size_t)((char*)(sums + 256) - (char*)cnt);
    hipMemsetAsync(cnt, 0, zlen, stream);

    k_prep_part<<<NCH + XBLK + WBLK, 256, 0, stream>>>(
        x, W1, W2, out_idx, in_idx, xbf, Wt1, Wt2, cnt, entries);

    k_conv<<<NB, 512, 0, stream>>>(xbf, Wt1, cnt, entries, y, sums);
    k_apply<<<NPTS * CC / 1024, 256, 0, stream>>>(y, sums, gamma1, beta1, xbf);  // a1 -> xbf
    k_conv<<<NB, 512, 0, stream>>>(xbf, Wt2, cnt, entries, y, sums + 128);
    k_final<<<NPTS * CC / 1024, 256, 0, stream>>>(y, x, sums + 128, gamma2, beta2, out);
}

// Round 14
// 350.209 us; speedup vs baseline: 3.1907x; 1.0748x over previous
//
#include <hip/hip_runtime.h>

#define NPTS 100000
#define CC   64
#define KK   27
#define TOT  (KK * NPTS)        // 2,700,000 edges
#define EPSBN 1e-5f
#define MT   128                // dst rows per conv block
#define NB   ((NPTS + MT - 1) / MT)   // 782 dst-blocks (= buckets per k)
#define CAP  200                // bucket capacity: Poisson(128) + 6.4 sigma

#define CHUNK  2500             // edges per partition block (divides NPTS; /4 exact)
#define NCH    (TOT / CHUNK)    // 1080 chunks total -> 4.2 blocks/CU

#define XBLK   (NPTS * CC / 1024)       // 6250 blocks for x conversion
#define WBLK   (2 * KK * CC * CC / 256) // 864 blocks for W prep

// fixed-point scale for the LDS integer accumulator (ds_add_u32 is native;
// fp32 LDS atomicAdd compiles to a CAS retry loop -> 7x slowdown, round 1)
#define FPSCALE 262144.0f               // 2^18
#define FPINV   3.814697265625e-06f     // 2^-18
#define FPMAGIC 12582912.0f             // 1.5 * 2^23
#define FPBITS  0x4B400000

typedef float          f32x4  __attribute__((ext_vector_type(4)));
typedef short          bf16x8 __attribute__((ext_vector_type(8)));
typedef unsigned int   u32x4  __attribute__((ext_vector_type(4)));
typedef unsigned short u16x4  __attribute__((ext_vector_type(4)));
typedef int            i32x4  __attribute__((ext_vector_type(4)));

__device__ __forceinline__ unsigned short f2bf(float f) {
    unsigned int u = __float_as_uint(f);
    u = (u + 0x7fffu + ((u >> 16) & 1u)) >> 16;
    return (unsigned short)u;
}

__device__ __forceinline__ int f2fix(float v) {
    return __float_as_int(fmaf(v, FPSCALE, FPMAGIC)) - FPBITS;
}

// ------------- fused prep (x->bf16, W->Wt) + single-pass CSR partition ------------
// Partition blocks FIRST (b < NCH): they are the long pole.
// Single-read staging: (d,s) go to LDS during the hist pass; placement pass reads
// LDS instead of re-reading 21.6 MB of global idx arrays (r13 did 2 global passes).
__global__ __launch_bounds__(256) void k_prep_part(
    const float* __restrict__ x,
    const float* __restrict__ W1, const float* __restrict__ W2,
    const int* __restrict__ out_idx, const int* __restrict__ in_idx,
    unsigned short* __restrict__ xb,
    unsigned short* __restrict__ Wt1, unsigned short* __restrict__ Wt2,
    int* __restrict__ cnt, unsigned* __restrict__ entries) {
    __shared__ int lc[NB];
    __shared__ __align__(16) int sdd[CHUNK];   // 10 KB staged dsts
    __shared__ __align__(16) int sds[CHUNK];   // 10 KB staged srcs
    const int t = threadIdx.x;
    int b = blockIdx.x;
    if (b >= NCH) {
        b -= NCH;
        if (b < XBLK) {
            int id = b * 256 + t;
            f32x4 v = ((const f32x4*)x)[id];
            u16x4 o;
#pragma unroll
            for (int j = 0; j < 4; ++j) o[j] = f2bf(v[j]);
            ((u16x4*)xb)[id] = o;
        } else {
            int id = (b - XBLK) * 256 + t;
            int which = id / (KK * CC * CC);
            int r = id % (KK * CC * CC);
            int k = r / (CC * CC);
            int rem = r % (CC * CC);
            int cin = rem / CC, cout = rem % CC;
            const float* W = which ? W2 : W1;
            unsigned short* Wt = which ? Wt2 : Wt1;
            Wt[k * CC * CC + cout * CC + cin] = f2bf(W[r]);
        }
        return;
    }
    for (int i = t; i < NB; i += 256) lc[i] = 0;
    __syncthreads();
    const int j0 = b * CHUNK;
    const int k  = j0 / NPTS;                  // CHUNK divides NPTS
    const i32x4* dsrc = (const i32x4*)(out_idx + j0);
    const i32x4* ssrc = (const i32x4*)(in_idx + j0);
    for (int ii = t; ii < CHUNK / 4; ii += 256) {
        i32x4 d = dsrc[ii];
        i32x4 s = ssrc[ii];
        ((i32x4*)sdd)[ii] = d;
        ((i32x4*)sds)[ii] = s;
#pragma unroll
        for (int q = 0; q < 4; ++q) atomicAdd(&lc[d[q] >> 7], 1);
    }
    __syncthreads();
    for (int i = t; i < NB; i += 256)
        lc[i] = atomicAdd(&cnt[k * NB + i], lc[i]);   // lc[i] := global base
    __syncthreads();
    for (int i = t; i < CHUNK; i += 256) {
        int d = sdd[i];
        int s = sds[i];
        int bb = d >> 7;
        int pos = atomicAdd(&lc[bb], 1);
        if (pos < CAP)
            entries[(size_t)(k * NB + bb) * CAP + pos] =
                ((unsigned)(d & 127) << 17) | (unsigned)s;
    }
}

// ---------------- conv: round-7 body + full 2-bit LDS scatter swizzle --------------
// 512 threads = 8 waves/block; wave w handles k = w, w+8, ...
// 3-stage gather pipeline; scatter rows from eg regs via width-16 shuffles.
// Scatter swizzle: channel col stored at col ^ ((row&3)<<3) -- spreads the 4 rows
// of one ds_add instruction across bank-starts {0,8,16,24} -> uniform 2-way (free),
// vs r13's 1-bit swizzle which left same-parity quads colliding (2.66M conflicts).
// launch_bounds(512,4): VGPR cap 128. NEVER request waves/EU the allocator can't
// meet: (256,5)->48 VGPR/140MB scratch (r3); (512,6)->40 VGPR/1.4GB scratch (r5).
__global__ __launch_bounds__(512, 4) void k_conv(
    const unsigned short* __restrict__ xb,    // [N][64] bf16
    const unsigned short* __restrict__ Wt,    // [27][cout=64][cin=64] bf16
    const int* __restrict__ cnt,              // [KK*NB] bucket counts
    const unsigned* __restrict__ entries,     // [KK*NB*CAP]: (dloc7<<17)|src17
    float* __restrict__ y,                    // [N][64] fp32
    float* __restrict__ sums)                 // [128]: sum, sumsq per channel
{
    __shared__ int ylds[MT * 64];             // 32768 B

    const int tid  = threadIdx.x;
    const int lane = tid & 63;
    const int wave = tid >> 6;                // 0..7
    const int quad = lane >> 4;
    const int l16  = lane & 15;
    const int blk  = blockIdx.x;
    const int i0   = blk << 7;

    for (int i = tid; i < MT * 64; i += 512) ylds[i] = 0;
    __syncthreads();

    const unsigned short* xq = xb + quad * 8;

    for (int k = wave; k < KK; k += 8) {
        const int bkt   = k * NB + blk;
        const size_t start = (size_t)bkt * CAP;
        int E = cnt[bkt];
        E = E > CAP ? CAP : E;
        if (E == 0) continue;
        const int emax = E - 1;

        // B fragments straight from global Wt (221 KB total, L2-hot)
        bf16x8 bfr[4][2];
        const unsigned short* wk = Wt + k * (CC * CC) + l16 * CC + quad * 8;
#pragma unroll
        for (int nt = 0; nt < 4; ++nt) {
            bfr[nt][0] = *(const bf16x8*)(wk + nt * 16 * CC);
            bfr[nt][1] = *(const bf16x8*)(wk + nt * 16 * CC + 32);
        }

        const int ntile = (E + 31) >> 5;

        // ---- pipeline prologue: eg queue 4 deep, fragments 3 deep ----
        unsigned eA0 = entries[start + min(l16, emax)];
        unsigned eB0 = entries[start + min(16 + l16, emax)];
        bf16x8 fc[2][2], fn[2][2];
        {
            const unsigned short* p0 = xq + (eA0 & 0x1FFFFu) * CC;
            const unsigned short* p1 = xq + (eB0 & 0x1FFFFu) * CC;
            fc[0][0] = *(const bf16x8*)p0;
            fc[0][1] = *(const bf16x8*)(p0 + 32);
            fc[1][0] = *(const bf16x8*)p1;
            fc[1][1] = *(const bf16x8*)(p1 + 32);
        }
        unsigned eA1 = entries[start + min(32 + l16, emax)];
        unsigned eB1 = entries[start + min(48 + l16, emax)];
        {
            const unsigned short* p0 = xq + (eA1 & 0x1FFFFu) * CC;
            const unsigned short* p1 = xq + (eB1 & 0x1FFFFu) * CC;
            fn[0][0] = *(const bf16x8*)p0;
            fn[0][1] = *(const bf16x8*)(p0 + 32);
            fn[1][0] = *(const bf16x8*)p1;
            fn[1][1] = *(const bf16x8*)(p1 + 32);
        }
        unsigned eA2 = entries[start + min(64 + l16, emax)];
        unsigned eB2 = entries[start + min(80 + l16, emax)];

        for (int t = 0; t < ntile; ++t) {
            const int tb = t * 32;
            // scatter rows for THIS tile from resident eg regs (width-16 shuffle)
            unsigned dp[2][4];
#pragma unroll
            for (int rr = 0; rr < 4; ++rr) {
                dp[0][rr] = (unsigned)__shfl((int)eA0, quad * 4 + rr, 16);
                dp[1][rr] = (unsigned)__shfl((int)eB0, quad * 4 + rr, 16);
            }
            // issue gather for tile t+2 from resident indices
            bf16x8 fp[2][2];
            {
                const unsigned short* p0 = xq + (eA2 & 0x1FFFFu) * CC;
                const unsigned short* p1 = xq + (eB2 & 0x1FFFFu) * CC;
                fp[0][0] = *(const bf16x8*)p0;
                fp[0][1] = *(const bf16x8*)(p0 + 32);
                fp[1][0] = *(const bf16x8*)p1;
                fp[1][1] = *(const bf16x8*)(p1 + 32);
            }
            // prefetch indices for tile t+3
            unsigned eA3 = entries[start + min(tb + 96 + l16, emax)];
            unsigned eB3 = entries[start + min(tb + 112 + l16, emax)];

            f32x4 acc[2][4];
#pragma unroll
            for (int mt = 0; mt < 2; ++mt)
#pragma unroll
                for (int nt = 0; nt < 4; ++nt) acc[mt][nt] = (f32x4){0.f, 0.f, 0.f, 0.f};
            __builtin_amdgcn_s_setprio(1);
#pragma unroll
            for (int mt = 0; mt < 2; ++mt)
#pragma unroll
                for (int nt = 0; nt < 4; ++nt) {
                    acc[mt][nt] = __builtin_amdgcn_mfma_f32_16x16x32_bf16(
                        fc[mt][0], bfr[nt][0], acc[mt][nt], 0, 0, 0);
                    acc[mt][nt] = __builtin_amdgcn_mfma_f32_16x16x32_bf16(
                        fc[mt][1], bfr[nt][1], acc[mt][nt], 0, 0, 0);
                }
            __builtin_amdgcn_s_setprio(0);

            // scatter: 32 native ds_add_u32 per lane per tile (fixed-point, swizzled)
#pragma unroll
            for (int mt = 0; mt < 2; ++mt)
#pragma unroll
                for (int rr = 0; rr < 4; ++rr) {
                    int slot = tb + mt * 16 + quad * 4 + rr;
                    if (slot < E) {
                        int row = (int)(dp[mt][rr] >> 17);
                        int s3 = (row & 1) << 3;   // bit 3 of column
                        int s4 = (row & 2) << 3;   // bit 4 of column
                        unsigned* yp = (unsigned*)&ylds[row * 64 + (l16 ^ s3)];
                        atomicAdd(yp + (0  ^ s4), (unsigned)f2fix(acc[mt][0][rr]));
                        atomicAdd(yp + (16 ^ s4), (unsigned)f2fix(acc[mt][1][rr]));
                        atomicAdd(yp + (32 ^ s4), (unsigned)f2fix(acc[mt][2][rr]));
                        atomicAdd(yp + (48 ^ s4), (unsigned)f2fix(acc[mt][3][rr]));
                    }
                }
            // rotate pipeline
            fc[0][0] = fn[0][0]; fc[0][1] = fn[0][1];
            fc[1][0] = fn[1][0]; fc[1][1] = fn[1][1];
            fn[0][0] = fp[0][0]; fn[0][1] = fp[0][1];
            fn[1][0] = fp[1][0]; fn[1][1] = fp[1][1];
            eA0 = eA1; eB0 = eB1;
            eA1 = eA2; eB1 = eB2;
            eA2 = eA3; eB2 = eB3;
        }
    }
    __syncthreads();

    // epilogue: write y + fused BN partial sums (ylds reused as scratch after reads)
    const int col = tid & 63;
    const int rg  = tid >> 6;                 // 0..7 -> 16 rows each
    float s = 0.f, q = 0.f;
#pragma unroll
    for (int i = 0; i < 16; ++i) {
        int row = rg * 16 + i;
        float v = (float)ylds[row * 64 + (col ^ ((row & 3) << 3))] * FPINV;
        int gr = i0 + row;
        if (gr < NPTS) y[(long)gr * CC + col] = v;
        s += v; q += v * v;
    }
    __syncthreads();                      // all ylds reads done
    float* ps = (float*)ylds;
    ps[rg * 128 + col] = s;
    ps[rg * 128 + 64 + col] = q;
    __syncthreads();
    if (tid < 128) {
        int which = tid >> 6, c = tid & 63;
        float a = 0.f;
#pragma unroll
        for (int wv = 0; wv < 8; ++wv) a += ps[wv * 128 + which * 64 + c];
        atomicAdd(&sums[which * 64 + c], a);
    }
}

// ---------------- a1 = bf16(relu(y*s + b)) with inline BN finalize ----------------
__global__ void k_apply(const float* __restrict__ y, const float* __restrict__ sums,
                        const float* __restrict__ gamma, const float* __restrict__ beta,
                        unsigned short* __restrict__ ab) {
    __shared__ float sb[128];
    int t = threadIdx.x;
    if (t < 64) {
        float mu  = sums[t] * (1.0f / NPTS);
        float var = sums[t + 64] * (1.0f / NPTS) - mu * mu;
        float s = gamma[t] * rsqrtf(var + EPSBN);
        sb[t] = s;
        sb[t + 64] = beta[t] - mu * s;
    }
    __syncthreads();
    int id = blockIdx.x * 256 + t;
    f32x4 v = ((const f32x4*)y)[id];
    int c0 = (id * 4) & 63;
    u16x4 o;
#pragma unroll
    for (int j = 0; j < 4; ++j) {
        float r = fmaxf(v[j] * sb[c0 + j] + sb[64 + c0 + j], 0.f);
        o[j] = f2bf(r);
    }
    ((u16x4*)ab)[id] = o;
}

// ---------------- out = relu(y*s + b + x) with inline BN finalize ----------------
__global__ void k_final(const float* __restrict__ y, const float* __restrict__ x,
                        const float* __restrict__ sums,
                        const float* __restrict__ gamma, const float* __restrict__ beta,
                        float* __restrict__ out) {
    __shared__ float sb[128];
    int t = threadIdx.x;
    if (t < 64) {
        float mu  = sums[t] * (1.0f / NPTS);
        float var = sums[t + 64] * (1.0f / NPTS) - mu * mu;
        float s = gamma[t] * rsqrtf(var + EPSBN);
        sb[t] = s;
        sb[t + 64] = beta[t] - mu * s;
    }
    __syncthreads();
    int id = blockIdx.x * 256 + t;
    f32x4 v  = ((const f32x4*)y)[id];
    f32x4 xv = ((const f32x4*)x)[id];
    int c0 = (id * 4) & 63;
    f32x4 o;
#pragma unroll
    for (int j = 0; j < 4; ++j)
        o[j] = fmaxf(v[j] * sb[c0 + j] + sb[64 + c0 + j] + xv[j], 0.f);
    ((f32x4*)out)[id] = o;
}

extern "C" void kernel_launch(void* const* d_in, const int* in_sizes, int n_in,
                              void* d_out, int out_size, void* d_ws, size_t ws_size,
                              hipStream_t stream) {
    const float* x      = (const float*)d_in[0];
    // d_in[1] = norm_points (unused by the reference math)
    const float* W1     = (const float*)d_in[2];
    const float* gamma1 = (const float*)d_in[3];
    const float* beta1  = (const float*)d_in[4];
    const float* W2     = (const float*)d_in[5];
    const float* gamma2 = (const float*)d_in[6];
    const float* beta2  = (const float*)d_in[7];
    const int* in_idx   = (const int*)d_in[8];
    const int* out_idx  = (const int*)d_in[9];
    float* out = (float*)d_out;

    char* w = (char*)d_ws;
    size_t off = 0;
    auto alloc = [&](size_t bytes) -> char* {
        off = (off + 255) & ~(size_t)255;
        char* p = w + off;
        off += bytes;
        return p;
    };
    int*   cnt       = (int*)     alloc((size_t)KK * NB * 4);
    float* sums      = (float*)   alloc(256 * 4);   // [0:128) layer1, [128:256) layer2
    unsigned* entries = (unsigned*)alloc((size_t)KK * NB * CAP * 4);
    unsigned short* xbf = (unsigned short*)alloc((size_t)NPTS * CC * 2);
    unsigned short* Wt1 = (unsigned short*)alloc((size_t)KK * CC * CC * 2);
    unsigned short* Wt2 = (unsigned short*)alloc((size_t)KK * CC * CC * 2);
    float* y = (float*)alloc((size_t)NPTS * CC * 4);

    // zero cnt + sums in one shot (contiguous allocations incl. alignment gap)
    size_t zlen = (size_t)((char*)(sums + 256) - (char*)cnt);
    hipMemsetAsync(cnt, 0, zlen, stream);

    k_prep_part<<<NCH + XBLK + WBLK, 256, 0, stream>>>(
        x, W1, W2, out_idx, in_idx, xbf, Wt1, Wt2, cnt, entries);

    k_conv<<<NB, 512, 0, stream>>>(xbf, Wt1, cnt, entries, y, sums);
    k_apply<<<NPTS * CC / 1024, 256, 0, stream>>>(y, sums, gamma1, beta1, xbf);  // a1 -> xbf
    k_conv<<<NB, 512, 0, stream>>>(xbf, Wt2, cnt, entries, y, sums + 128);
    k_final<<<NPTS * CC / 1024, 256, 0, stream>>>(y, x, sums + 128, gamma2, beta2, out);
}

// Round 16
// 349.546 us; speedup vs baseline: 3.1968x; 1.0019x over previous
//
#include <hip/hip_runtime.h>

#define NPTS 100000
#define CC   64
#define KK   27
#define TOT  (KK * NPTS)        // 2,700,000 edges
#define EPSBN 1e-5f
#define MT   128                // dst rows per conv block
#define NB   ((NPTS + MT - 1) / MT)   // 782 dst-blocks (= buckets per k)
#define CAP  200                // bucket capacity: Poisson(128) + 6.4 sigma

#define CHUNK  1000             // edges per partition block (divides NPTS; /4 exact)
#define NCH    (TOT / CHUNK)    // 2700 chunks -> 10.5 blocks/CU (r13: 4.2, r12: 0.84)

#define XBLK   (NPTS * CC / 1024)       // 6250 blocks for x conversion
#define WBLK   (2 * KK * CC * CC / 256) // 864 blocks for W prep

// fixed-point scale for the LDS integer accumulator (ds_add_u32 is native;
// fp32 LDS atomicAdd compiles to a CAS retry loop -> 7x slowdown, round 1)
#define FPSCALE 262144.0f               // 2^18
#define FPINV   3.814697265625e-06f     // 2^-18
#define FPMAGIC 12582912.0f             // 1.5 * 2^23
#define FPBITS  0x4B400000

typedef float          f32x4  __attribute__((ext_vector_type(4)));
typedef short          bf16x8 __attribute__((ext_vector_type(8)));
typedef unsigned int   u32x4  __attribute__((ext_vector_type(4)));
typedef unsigned short u16x4  __attribute__((ext_vector_type(4)));
typedef int            i32x4  __attribute__((ext_vector_type(4)));

__device__ __forceinline__ unsigned short f2bf(float f) {
    unsigned int u = __float_as_uint(f);
    u = (u + 0x7fffu + ((u >> 16) & 1u)) >> 16;
    return (unsigned short)u;
}

__device__ __forceinline__ int f2fix(float v) {
    return __float_as_int(fmaf(v, FPSCALE, FPMAGIC)) - FPBITS;
}

// ------------- fused prep (x->bf16, W->Wt) + single-pass CSR partition ------------
// Partition blocks FIRST (b < NCH): they are the long pole (scattered 4B entry
// writes + atomics, latency-bound -> parallelism is the lever: r12->r13 0.84->4.2
// blocks/CU cut it 126 -> ~90 us). CHUNK=1000 -> 10.5 blocks/CU.
// Single-read staging: (d,s) go to LDS during the hist pass; placement reads LDS.
// Zero-skip: ~28% of buckets have 0 entries per 1000-edge chunk -> skip their
// global reservation atomicAdd.
__global__ __launch_bounds__(256) void k_prep_part(
    const float* __restrict__ x,
    const float* __restrict__ W1, const float* __restrict__ W2,
    const int* __restrict__ out_idx, const int* __restrict__ in_idx,
    unsigned short* __restrict__ xb,
    unsigned short* __restrict__ Wt1, unsigned short* __restrict__ Wt2,
    int* __restrict__ cnt, unsigned* __restrict__ entries) {
    __shared__ int lc[NB];
    __shared__ __align__(16) int sdd[CHUNK];   // 4 KB staged dsts
    __shared__ __align__(16) int sds[CHUNK];   // 4 KB staged srcs
    const int t = threadIdx.x;
    int b = blockIdx.x;
    if (b >= NCH) {
        b -= NCH;
        if (b < XBLK) {
            int id = b * 256 + t;
            f32x4 v = ((const f32x4*)x)[id];
            u16x4 o;
#pragma unroll
            for (int j = 0; j < 4; ++j) o[j] = f2bf(v[j]);
            ((u16x4*)xb)[id] = o;
        } else {
            int id = (b - XBLK) * 256 + t;
            int which = id / (KK * CC * CC);
            int r = id % (KK * CC * CC);
            int k = r / (CC * CC);
            int rem = r % (CC * CC);
            int cin = rem / CC, cout = rem % CC;
            const float* W = which ? W2 : W1;
            unsigned short* Wt = which ? Wt2 : Wt1;
            Wt[k * CC * CC + cout * CC + cin] = f2bf(W[r]);
        }
        return;
    }
    for (int i = t; i < NB; i += 256) lc[i] = 0;
    __syncthreads();
    const int j0 = b * CHUNK;
    const int k  = j0 / NPTS;                  // CHUNK divides NPTS
    const i32x4* dsrc = (const i32x4*)(out_idx + j0);
    const i32x4* ssrc = (const i32x4*)(in_idx + j0);
    for (int ii = t; ii < CHUNK / 4; ii += 256) {
        i32x4 d = dsrc[ii];
        i32x4 s = ssrc[ii];
        ((i32x4*)sdd)[ii] = d;
        ((i32x4*)sds)[ii] = s;
#pragma unroll
        for (int q = 0; q < 4; ++q) atomicAdd(&lc[d[q] >> 7], 1);
    }
    __syncthreads();
    for (int i = t; i < NB; i += 256) {
        int v = lc[i];
        lc[i] = v ? atomicAdd(&cnt[k * NB + i], v) : 0;   // lc[i] := global base
    }
    __syncthreads();
    for (int i = t; i < CHUNK; i += 256) {
        int d = sdd[i];
        int s = sds[i];
        int bb = d >> 7;
        int pos = atomicAdd(&lc[bb], 1);
        if (pos < CAP)
            entries[(size_t)(k * NB + bb) * CAP + pos] =
                ((unsigned)(d & 127) << 17) | (unsigned)s;
    }
}

// ---------------- conv: round-7 body (109 us steady-state, fabric-pinned) ----------
// 512 threads = 8 waves/block; wave w handles k = w, w+8, ...
// 3-stage gather pipeline; scatter rows from eg regs via width-16 shuffles.
// Scatter swizzle col ^ ((row&3)<<3): conflicts ~2.65M are irreducible under this
// write shape (4 quads x 16-bank windows on 32 banks; r14 null confirmed).
// launch_bounds(512,4): VGPR cap 128. NEVER request waves/EU the allocator can't
// meet: (256,5)->48 VGPR/140MB scratch (r3); (512,6)->40 VGPR/1.4GB scratch (r5).
__global__ __launch_bounds__(512, 4) void k_conv(
    const unsigned short* __restrict__ xb,    // [N][64] bf16
    const unsigned short* __restrict__ Wt,    // [27][cout=64][cin=64] bf16
    const int* __restrict__ cnt,              // [KK*NB] bucket counts
    const unsigned* __restrict__ entries,     // [KK*NB*CAP]: (dloc7<<17)|src17
    float* __restrict__ y,                    // [N][64] fp32
    float* __restrict__ sums)                 // [128]: sum, sumsq per channel
{
    __shared__ int ylds[MT * 64];             // 32768 B

    const int tid  = threadIdx.x;
    const int lane = tid & 63;
    const int wave = tid >> 6;                // 0..7
    const int quad = lane >> 4;
    const int l16  = lane & 15;
    const int blk  = blockIdx.x;
    const int i0   = blk << 7;

    for (int i = tid; i < MT * 64; i += 512) ylds[i] = 0;
    __syncthreads();

    const unsigned short* xq = xb + quad * 8;

    for (int k = wave; k < KK; k += 8) {
        const int bkt   = k * NB + blk;
        const size_t start = (size_t)bkt * CAP;
        int E = cnt[bkt];
        E = E > CAP ? CAP : E;
        if (E == 0) continue;
        const int emax = E - 1;

        // B fragments straight from global Wt (221 KB total, L2-hot)
        bf16x8 bfr[4][2];
        const unsigned short* wk = Wt + k * (CC * CC) + l16 * CC + quad * 8;
#pragma unroll
        for (int nt = 0; nt < 4; ++nt) {
            bfr[nt][0] = *(const bf16x8*)(wk + nt * 16 * CC);
            bfr[nt][1] = *(const bf16x8*)(wk + nt * 16 * CC + 32);
        }

        const int ntile = (E + 31) >> 5;

        // ---- pipeline prologue: eg queue 4 deep, fragments 3 deep ----
        unsigned eA0 = entries[start + min(l16, emax)];
        unsigned eB0 = entries[start + min(16 + l16, emax)];
        bf16x8 fc[2][2], fn[2][2];
        {
            const unsigned short* p0 = xq + (eA0 & 0x1FFFFu) * CC;
            const unsigned short* p1 = xq + (eB0 & 0x1FFFFu) * CC;
            fc[0][0] = *(const bf16x8*)p0;
            fc[0][1] = *(const bf16x8*)(p0 + 32);
            fc[1][0] = *(const bf16x8*)p1;
            fc[1][1] = *(const bf16x8*)(p1 + 32);
        }
        unsigned eA1 = entries[start + min(32 + l16, emax)];
        unsigned eB1 = entries[start + min(48 + l16, emax)];
        {
            const unsigned short* p0 = xq + (eA1 & 0x1FFFFu) * CC;
            const unsigned short* p1 = xq + (eB1 & 0x1FFFFu) * CC;
            fn[0][0] = *(const bf16x8*)p0;
            fn[0][1] = *(const bf16x8*)(p0 + 32);
            fn[1][0] = *(const bf16x8*)p1;
            fn[1][1] = *(const bf16x8*)(p1 + 32);
        }
        unsigned eA2 = entries[start + min(64 + l16, emax)];
        unsigned eB2 = entries[start + min(80 + l16, emax)];

        for (int t = 0; t < ntile; ++t) {
            const int tb = t * 32;
            // scatter rows for THIS tile from resident eg regs (width-16 shuffle)
            unsigned dp[2][4];
#pragma unroll
            for (int rr = 0; rr < 4; ++rr) {
                dp[0][rr] = (unsigned)__shfl((int)eA0, quad * 4 + rr, 16);
                dp[1][rr] = (unsigned)__shfl((int)eB0, quad * 4 + rr, 16);
            }
            // issue gather for tile t+2 from resident indices
            bf16x8 fp[2][2];
            {
                const unsigned short* p0 = xq + (eA2 & 0x1FFFFu) * CC;
                const unsigned short* p1 = xq + (eB2 & 0x1FFFFu) * CC;
                fp[0][0] = *(const bf16x8*)p0;
                fp[0][1] = *(const bf16x8*)(p0 + 32);
                fp[1][0] = *(const bf16x8*)p1;
                fp[1][1] = *(const bf16x8*)(p1 + 32);
            }
            // prefetch indices for tile t+3
            unsigned eA3 = entries[start + min(tb + 96 + l16, emax)];
            unsigned eB3 = entries[start + min(tb + 112 + l16, emax)];

            f32x4 acc[2][4];
#pragma unroll
            for (int mt = 0; mt < 2; ++mt)
#pragma unroll
                for (int nt = 0; nt < 4; ++nt) acc[mt][nt] = (f32x4){0.f, 0.f, 0.f, 0.f};
            __builtin_amdgcn_s_setprio(1);
#pragma unroll
            for (int mt = 0; mt < 2; ++mt)
#pragma unroll
                for (int nt = 0; nt < 4; ++nt) {
                    acc[mt][nt] = __builtin_amdgcn_mfma_f32_16x16x32_bf16(
                        fc[mt][0], bfr[nt][0], acc[mt][nt], 0, 0, 0);
                    acc[mt][nt] = __builtin_amdgcn_mfma_f32_16x16x32_bf16(
                        fc[mt][1], bfr[nt][1], acc[mt][nt], 0, 0, 0);
                }
            __builtin_amdgcn_s_setprio(0);

            // scatter: 32 native ds_add_u32 per lane per tile (fixed-point, swizzled)
#pragma unroll
            for (int mt = 0; mt < 2; ++mt)
#pragma unroll
                for (int rr = 0; rr < 4; ++rr) {
                    int slot = tb + mt * 16 + quad * 4 + rr;
                    if (slot < E) {
                        int row = (int)(dp[mt][rr] >> 17);
                        int s3 = (row & 1) << 3;   // bit 3 of column
                        int s4 = (row & 2) << 3;   // bit 4 of column
                        unsigned* yp = (unsigned*)&ylds[row * 64 + (l16 ^ s3)];
                        atomicAdd(yp + (0  ^ s4), (unsigned)f2fix(acc[mt][0][rr]));
                        atomicAdd(yp + (16 ^ s4), (unsigned)f2fix(acc[mt][1][rr]));
                        atomicAdd(yp + (32 ^ s4), (unsigned)f2fix(acc[mt][2][rr]));
                        atomicAdd(yp + (48 ^ s4), (unsigned)f2fix(acc[mt][3][rr]));
                    }
                }
            // rotate pipeline
            fc[0][0] = fn[0][0]; fc[0][1] = fn[0][1];
            fc[1][0] = fn[1][0]; fc[1][1] = fn[1][1];
            fn[0][0] = fp[0][0]; fn[0][1] = fp[0][1];
            fn[1][0] = fp[1][0]; fn[1][1] = fp[1][1];
            eA0 = eA1; eB0 = eB1;
            eA1 = eA2; eB1 = eB2;
            eA2 = eA3; eB2 = eB3;
        }
    }
    __syncthreads();

    // epilogue: write y + fused BN partial sums (ylds reused as scratch after reads)
    const int col = tid & 63;
    const int rg  = tid >> 6;                 // 0..7 -> 16 rows each
    float s = 0.f, q = 0.f;
#pragma unroll
    for (int i = 0; i < 16; ++i) {
        int row = rg * 16 + i;
        float v = (float)ylds[row * 64 + (col ^ ((row & 3) << 3))] * FPINV;
        int gr = i0 + row;
        if (gr < NPTS) y[(long)gr * CC + col] = v;
        s += v; q += v * v;
    }
    __syncthreads();                      // all ylds reads done
    float* ps = (float*)ylds;
    ps[rg * 128 + col] = s;
    ps[rg * 128 + 64 + col] = q;
    __syncthreads();
    if (tid < 128) {
        int which = tid >> 6, c = tid & 63;
        float a = 0.f;
#pragma unroll
        for (int wv = 0; wv < 8; ++wv) a += ps[wv * 128 + which * 64 + c];
        atomicAdd(&sums[which * 64 + c], a);
    }
}

// ---------------- a1 = bf16(relu(y*s + b)) with inline BN finalize ----------------
__global__ void k_apply(const float* __restrict__ y, const float* __restrict__ sums,
                        const float* __restrict__ gamma, const float* __restrict__ beta,
                        unsigned short* __restrict__ ab) {
    __shared__ float sb[128];
    int t = threadIdx.x;
    if (t < 64) {
        float mu  = sums[t] * (1.0f / NPTS);
        float var = sums[t + 64] * (1.0f / NPTS) - mu * mu;
        float s = gamma[t] * rsqrtf(var + EPSBN);
        sb[t] = s;
        sb[t + 64] = beta[t] - mu * s;
    }
    __syncthreads();
    int id = blockIdx.x * 256 + t;
    f32x4 v = ((const f32x4*)y)[id];
    int c0 = (id * 4) & 63;
    u16x4 o;
#pragma unroll
    for (int j = 0; j < 4; ++j) {
        float r = fmaxf(v[j] * sb[c0 + j] + sb[64 + c0 + j], 0.f);
        o[j] = f2bf(r);
    }
    ((u16x4*)ab)[id] = o;
}

// ---------------- out = relu(y*s + b + x) with inline BN finalize ----------------
__global__ void k_final(const float* __restrict__ y, const float* __restrict__ x,
                        const float* __restrict__ sums,
                        const float* __restrict__ gamma, const float* __restrict__ beta,
                        float* __restrict__ out) {
    __shared__ float sb[128];
    int t = threadIdx.x;
    if (t < 64) {
        float mu  = sums[t] * (1.0f / NPTS);
        float var = sums[t + 64] * (1.0f / NPTS) - mu * mu;
        float s = gamma[t] * rsqrtf(var + EPSBN);
        sb[t] = s;
        sb[t + 64] = beta[t] - mu * s;
    }
    __syncthreads();
    int id = blockIdx.x * 256 + t;
    f32x4 v  = ((const f32x4*)y)[id];
    f32x4 xv = ((const f32x4*)x)[id];
    int c0 = (id * 4) & 63;
    f32x4 o;
#pragma unroll
    for (int j = 0; j < 4; ++j)
        o[j] = fmaxf(v[j] * sb[c0 + j] + sb[64 + c0 + j] + xv[j], 0.f);
    ((f32x4*)out)[id] = o;
}

extern "C" void kernel_launch(void* const* d_in, const int* in_sizes, int n_in,
                              void* d_out, int out_size, void* d_ws, size_t ws_size,
                              hipStream_t stream) {
    const float* x      = (const float*)d_in[0];
    // d_in[1] = norm_points (unused by the reference math)
    const float* W1     = (const float*)d_in[2];
    const float* gamma1 = (const float*)d_in[3];
    const float* beta1  = (const float*)d_in[4];
    const float* W2     = (const float*)d_in[5];
    const float* gamma2 = (const float*)d_in[6];
    const float* beta2  = (const float*)d_in[7];
    const int* in_idx   = (const int*)d_in[8];
    const int* out_idx  = (const int*)d_in[9];
    float* out = (float*)d_out;

    char* w = (char*)d_ws;
    size_t off = 0;
    auto alloc = [&](size_t bytes) -> char* {
        off = (off + 255) & ~(size_t)255;
        char* p = w + off;
        off += bytes;
        return p;
    };
    int*   cnt       = (int*)     alloc((size_t)KK * NB * 4);
    float* sums      = (float*)   alloc(256 * 4);   // [0:128) layer1, [128:256) layer2
    unsigned* entries = (unsigned*)alloc((size_t)KK * NB * CAP * 4);
    unsigned short* xbf = (unsigned short*)alloc((size_t)NPTS * CC * 2);
    unsigned short* Wt1 = (unsigned short*)alloc((size_t)KK * CC * CC * 2);
    unsigned short* Wt2 = (unsigned short*)alloc((size_t)KK * CC * CC * 2);
    float* y = (float*)alloc((size_t)NPTS * CC * 4);

    // zero cnt + sums in one shot (contiguous allocations incl. alignment gap)
    size_t zlen = (size_t)((char*)(sums + 256) - (char*)cnt);
    hipMemsetAsync(cnt, 0, zlen, stream);

    k_prep_part<<<NCH + XBLK + WBLK, 256, 0, stream>>>(
        x, W1, W2, out_idx, in_idx, xbf, Wt1, Wt2, cnt, entries);

    k_conv<<<NB, 512, 0, stream>>>(xbf, Wt1, cnt, entries, y, sums);
    k_apply<<<NPTS * CC / 1024, 256, 0, stream>>>(y, sums, gamma1, beta1, xbf);  // a1 -> xbf
    k_conv<<<NB, 512, 0, stream>>>(xbf, Wt2, cnt, entries, y, sums + 128);
    k_final<<<NPTS * CC / 1024, 256, 0, stream>>>(y, x, sums + 128, gamma2, beta2, out);
}